// Round 1
// baseline (1384.788 us; speedup 1.0000x reference)
//
#include <hip/hip_runtime.h>
#include <math.h>

// Problem constants (B=16, P=8192)
constexpr int Bn = 16, Pn = 8192, Nn = 16 * 8192, Cc = 256;

// ---------------------------------------------------------------------------
// kNN: per batch, brute-force top-4 smallest squared distances (self incl.)
// Tie-break: strict '<' while scanning ascending j  == jax.lax.top_k stability.
// ---------------------------------------------------------------------------
__global__ __launch_bounds__(256) void knn_kernel(const float* __restrict__ coords,
                                                  int* __restrict__ nbr) {
  __shared__ float2 sxy[Pn];  // 64 KB
  const int b = blockIdx.y;
  const int t = threadIdx.x;
  // cooperative load of the whole batch's coords (4096 float4)
  const float4* src = (const float4*)(coords + (size_t)b * Pn * 2);
  float4* dst = (float4*)sxy;
#pragma unroll
  for (int i = 0; i < 16; ++i) dst[t + i * 256] = src[t + i * 256];
  __syncthreads();

  const int qi = blockIdx.x * 256 + t;
  const float qx = sxy[qi].x, qy = sxy[qi].y;
  float d0 = 3.4e38f, d1 = 3.4e38f, d2 = 3.4e38f, d3 = 3.4e38f;
  int i0 = 0, i1 = 0, i2 = 0, i3 = 0;
#pragma unroll 4
  for (int j = 0; j < Pn; ++j) {
    float2 c = sxy[j];
    float dx = qx - c.x, dy = qy - c.y;
    // match XLA: dx*dx + dy*dy, no fma contraction
    float d = __fadd_rn(__fmul_rn(dx, dx), __fmul_rn(dy, dy));
    if (d < d3) {
      if (d < d2) {
        d3 = d2; i3 = i2;
        if (d < d1) {
          d2 = d1; i2 = i1;
          if (d < d0) { d1 = d0; i1 = i0; d0 = d; i0 = j; }
          else        { d1 = d;  i1 = j; }
        } else { d2 = d; i2 = j; }
      } else { d3 = d; i3 = j; }
    }
  }
  const int base = b * Pn;
  int4 outv = make_int4(base + i0, base + i1, base + i2, base + i3);
  *(int4*)&nbr[(size_t)(base + qi) * 4] = outv;
}

// ---------------------------------------------------------------------------
// f32 GEMM: A[M,256] @ W[256,256] -> C[M,256]; BM=BN=128, BK=16, 256 thr, 8x8
// ---------------------------------------------------------------------------
__global__ __launch_bounds__(256) void gemm_f32_256(const float* __restrict__ A,
                                                    const float* __restrict__ W,
                                                    float* __restrict__ C) {
  __shared__ float As[16][132];  // A^T tile, padded
  __shared__ float Bs[16][128];
  const int tid = threadIdx.x;
  const int row0 = blockIdx.y * 128;
  const int col0 = blockIdx.x * 128;
  const int tm = tid & 15, tn = tid >> 4;

  float acc[8][8];
#pragma unroll
  for (int i = 0; i < 8; ++i)
#pragma unroll
    for (int j = 0; j < 8; ++j) acc[i][j] = 0.f;

  const int ar = tid >> 2;         // 0..63
  const int ac = (tid & 3) * 4;    // 0,4,8,12
  const int bk = tid >> 5;         // 0..7
  const int bn = (tid & 31) * 4;   // 0..124

  for (int kt = 0; kt < 16; ++kt) {
    const int k0 = kt * 16;
    float4 a0 = *(const float4*)&A[(size_t)(row0 + ar) * 256 + k0 + ac];
    float4 a1 = *(const float4*)&A[(size_t)(row0 + ar + 64) * 256 + k0 + ac];
    float4 b0 = *(const float4*)&W[(size_t)(k0 + bk) * 256 + col0 + bn];
    float4 b1 = *(const float4*)&W[(size_t)(k0 + bk + 8) * 256 + col0 + bn];
    __syncthreads();
    As[ac + 0][ar] = a0.x; As[ac + 1][ar] = a0.y;
    As[ac + 2][ar] = a0.z; As[ac + 3][ar] = a0.w;
    As[ac + 0][ar + 64] = a1.x; As[ac + 1][ar + 64] = a1.y;
    As[ac + 2][ar + 64] = a1.z; As[ac + 3][ar + 64] = a1.w;
    *(float4*)&Bs[bk][bn] = b0;
    *(float4*)&Bs[bk + 8][bn] = b1;
    __syncthreads();
#pragma unroll
    for (int kk = 0; kk < 16; ++kk) {
      float a[8], bb[8];
      *(float4*)&a[0] = *(const float4*)&As[kk][tm * 8];
      *(float4*)&a[4] = *(const float4*)&As[kk][tm * 8 + 4];
      *(float4*)&bb[0] = *(const float4*)&Bs[kk][tn * 8];
      *(float4*)&bb[4] = *(const float4*)&Bs[kk][tn * 8 + 4];
#pragma unroll
      for (int i = 0; i < 8; ++i)
#pragma unroll
        for (int j = 0; j < 8; ++j) acc[i][j] = fmaf(a[i], bb[j], acc[i][j]);
    }
  }
#pragma unroll
  for (int i = 0; i < 8; ++i) {
    const size_t r = (size_t)(row0 + tm * 8 + i);
    float4 c0 = make_float4(acc[i][0], acc[i][1], acc[i][2], acc[i][3]);
    float4 c1 = make_float4(acc[i][4], acc[i][5], acc[i][6], acc[i][7]);
    *(float4*)&C[r * 256 + col0 + tn * 8] = c0;
    *(float4*)&C[r * 256 + col0 + tn * 8 + 4] = c1;
  }
}

// ---------------------------------------------------------------------------
// asrc[n,h] = sum_f g[n, h*64+f] * att_src[h,f]; same for adst. One wave/node.
// ---------------------------------------------------------------------------
__global__ __launch_bounds__(256) void attn_coeff_kernel(const float* __restrict__ g,
                                                         const float* __restrict__ att_src,
                                                         const float* __restrict__ att_dst,
                                                         float* __restrict__ asrc,
                                                         float* __restrict__ adst) {
  const int t = threadIdx.x;
  const int lane = t & 63;
  const int n = blockIdx.x * 4 + (t >> 6);
  float4 v  = *(const float4*)&g[(size_t)n * 256 + lane * 4];
  float4 as = *(const float4*)&att_src[lane * 4];  // h*64 + (lane%16)*4 == lane*4
  float4 ad = *(const float4*)&att_dst[lane * 4];
  float ps = v.x * as.x + v.y * as.y + v.z * as.z + v.w * as.w;
  float pd = v.x * ad.x + v.y * ad.y + v.z * ad.z + v.w * ad.w;
#pragma unroll
  for (int off = 1; off < 16; off <<= 1) {
    ps += __shfl_xor(ps, off);
    pd += __shfl_xor(pd, off);
  }
  if ((lane & 15) == 0) {
    asrc[(size_t)n * 4 + (lane >> 4)] = ps;
    adst[(size_t)n * 4 + (lane >> 4)] = pd;
  }
}

__device__ __forceinline__ float leaky02(float x) { return x >= 0.f ? x : 0.2f * x; }

// ---------------------------------------------------------------------------
// alpha[n, j, h] = softmax_j leaky(asrc[nbr_j,h] + adst[n,h])   (H=4, k=4)
// ---------------------------------------------------------------------------
__global__ __launch_bounds__(256) void alpha_kernel(const int* __restrict__ nbr,
                                                    const float* __restrict__ asrc,
                                                    const float* __restrict__ adst,
                                                    float* __restrict__ alpha) {
  const int n = blockIdx.x * 256 + threadIdx.x;
  int4 nb = *(const int4*)&nbr[(size_t)n * 4];
  float4 ad = *(const float4*)&adst[(size_t)n * 4];
  int idx[4] = {nb.x, nb.y, nb.z, nb.w};
  float4 e[4];
#pragma unroll
  for (int j = 0; j < 4; ++j) {
    float4 as = *(const float4*)&asrc[(size_t)idx[j] * 4];
    e[j].x = leaky02(as.x + ad.x);
    e[j].y = leaky02(as.y + ad.y);
    e[j].z = leaky02(as.z + ad.z);
    e[j].w = leaky02(as.w + ad.w);
  }
  float4 m = e[0];
#pragma unroll
  for (int j = 1; j < 4; ++j) {
    m.x = fmaxf(m.x, e[j].x); m.y = fmaxf(m.y, e[j].y);
    m.z = fmaxf(m.z, e[j].z); m.w = fmaxf(m.w, e[j].w);
  }
  float4 s = make_float4(0.f, 0.f, 0.f, 0.f);
#pragma unroll
  for (int j = 0; j < 4; ++j) {
    e[j].x = expf(e[j].x - m.x); e[j].y = expf(e[j].y - m.y);
    e[j].z = expf(e[j].z - m.z); e[j].w = expf(e[j].w - m.w);
    s.x += e[j].x; s.y += e[j].y; s.z += e[j].z; s.w += e[j].w;
  }
#pragma unroll
  for (int j = 0; j < 4; ++j) {
    float4 o = make_float4(e[j].x / s.x, e[j].y / s.y, e[j].z / s.z, e[j].w / s.w);
    *(float4*)&alpha[(size_t)n * 16 + j * 4] = o;
  }
}

// ---------------------------------------------------------------------------
// out[n, h*64+f] = sum_j alpha[n,j,h] * g[nbr_j, h*64+f] + bias; optional ELU.
// One wave per node; lane owns 4 consecutive features.
// ---------------------------------------------------------------------------
template <bool ELU>
__global__ __launch_bounds__(256) void aggregate_kernel(const float* __restrict__ g,
                                                        const int* __restrict__ nbr,
                                                        const float* __restrict__ alpha,
                                                        const float* __restrict__ bias,
                                                        float* __restrict__ y) {
  const int t = threadIdx.x;
  const int lane = t & 63;
  const int n = blockIdx.x * 4 + (t >> 6);
  int4 nb = *(const int4*)&nbr[(size_t)n * 4];
  const int h = lane >> 4;
  const float a0 = alpha[(size_t)n * 16 + 0 + h];
  const float a1 = alpha[(size_t)n * 16 + 4 + h];
  const float a2 = alpha[(size_t)n * 16 + 8 + h];
  const float a3 = alpha[(size_t)n * 16 + 12 + h];
  const int c = lane * 4;
  float4 v0 = *(const float4*)&g[(size_t)nb.x * 256 + c];
  float4 v1 = *(const float4*)&g[(size_t)nb.y * 256 + c];
  float4 v2 = *(const float4*)&g[(size_t)nb.z * 256 + c];
  float4 v3 = *(const float4*)&g[(size_t)nb.w * 256 + c];
  float4 bb = *(const float4*)&bias[c];
  float4 o;
  o.x = a0 * v0.x + a1 * v1.x + a2 * v2.x + a3 * v3.x + bb.x;
  o.y = a0 * v0.y + a1 * v1.y + a2 * v2.y + a3 * v3.y + bb.y;
  o.z = a0 * v0.z + a1 * v1.z + a2 * v2.z + a3 * v3.z + bb.z;
  o.w = a0 * v0.w + a1 * v1.w + a2 * v2.w + a3 * v3.w + bb.w;
  if (ELU) {
    o.x = o.x > 0.f ? o.x : expm1f(o.x);
    o.y = o.y > 0.f ? o.y : expm1f(o.y);
    o.z = o.z > 0.f ? o.z : expm1f(o.z);
    o.w = o.w > 0.f ? o.w : expm1f(o.w);
  }
  *(float4*)&y[(size_t)n * 256 + c] = o;
}

// ---------------------------------------------------------------------------
// Layer 2 projection: g2[n,0..1] = y[n,:] @ W2[:,0..1]; also asrc2/adst2 scalars.
// One wave per node, full-wave reduction.
// ---------------------------------------------------------------------------
__global__ __launch_bounds__(256) void head2_kernel(const float* __restrict__ y,
                                                    const float* __restrict__ W2,
                                                    const float* __restrict__ as2,
                                                    const float* __restrict__ ad2,
                                                    float* __restrict__ g2,
                                                    float* __restrict__ asrc2,
                                                    float* __restrict__ adst2) {
  const int t = threadIdx.x, lane = t & 63;
  const int n = blockIdx.x * 4 + (t >> 6);
  float4 v  = *(const float4*)&y[(size_t)n * 256 + lane * 4];
  float4 wa = *(const float4*)&W2[lane * 8];      // rows 4l,4l+1 (cols 0,1 each)
  float4 wb = *(const float4*)&W2[lane * 8 + 4];  // rows 4l+2,4l+3
  float p0 = v.x * wa.x + v.y * wa.z + v.z * wb.x + v.w * wb.z;
  float p1 = v.x * wa.y + v.y * wa.w + v.z * wb.y + v.w * wb.w;
#pragma unroll
  for (int off = 1; off < 64; off <<= 1) {
    p0 += __shfl_xor(p0, off);
    p1 += __shfl_xor(p1, off);
  }
  if (lane == 0) {
    g2[(size_t)n * 2]     = p0;
    g2[(size_t)n * 2 + 1] = p1;
    asrc2[n] = p0 * as2[0] + p1 * as2[1];
    adst2[n] = p0 * ad2[0] + p1 * ad2[1];
  }
}

// ---------------------------------------------------------------------------
// Final aggregation (H=1, F=2) + bias -> d_out
// ---------------------------------------------------------------------------
__global__ __launch_bounds__(256) void final_kernel(const int* __restrict__ nbr,
                                                    const float* __restrict__ g2,
                                                    const float* __restrict__ asrc2,
                                                    const float* __restrict__ adst2,
                                                    const float* __restrict__ b2,
                                                    float* __restrict__ out) {
  const int n = blockIdx.x * 256 + threadIdx.x;
  int4 nb = *(const int4*)&nbr[(size_t)n * 4];
  const float ad = adst2[n];
  float e0 = leaky02(asrc2[nb.x] + ad);
  float e1 = leaky02(asrc2[nb.y] + ad);
  float e2 = leaky02(asrc2[nb.z] + ad);
  float e3 = leaky02(asrc2[nb.w] + ad);
  float m = fmaxf(fmaxf(e0, e1), fmaxf(e2, e3));
  float x0 = expf(e0 - m), x1 = expf(e1 - m), x2 = expf(e2 - m), x3 = expf(e3 - m);
  float s = x0 + x1 + x2 + x3;
  float o0 = (x0 * g2[(size_t)nb.x * 2] + x1 * g2[(size_t)nb.y * 2] +
              x2 * g2[(size_t)nb.z * 2] + x3 * g2[(size_t)nb.w * 2]) / s;
  float o1 = (x0 * g2[(size_t)nb.x * 2 + 1] + x1 * g2[(size_t)nb.y * 2 + 1] +
              x2 * g2[(size_t)nb.z * 2 + 1] + x3 * g2[(size_t)nb.w * 2 + 1]) / s;
  out[(size_t)n * 2]     = o0 + b2[0];
  out[(size_t)n * 2 + 1] = o1 + b2[1];
}

extern "C" void kernel_launch(void* const* d_in, const int* in_sizes, int n_in,
                              void* d_out, int out_size, void* d_ws, size_t ws_size,
                              hipStream_t stream) {
  const float* coords = (const float*)d_in[0];
  const float* x   = (const float*)d_in[1];
  const float* W0  = (const float*)d_in[2];
  const float* as0 = (const float*)d_in[3];
  const float* ad0 = (const float*)d_in[4];
  const float* b0  = (const float*)d_in[5];
  const float* W1  = (const float*)d_in[6];
  const float* as1 = (const float*)d_in[7];
  const float* ad1 = (const float*)d_in[8];
  const float* b1  = (const float*)d_in[9];
  const float* W2  = (const float*)d_in[10];
  const float* as2 = (const float*)d_in[11];
  const float* ad2 = (const float*)d_in[12];
  const float* b2  = (const float*)d_in[13];
  float* out = (float*)d_out;

  // workspace carve-up (~272 MiB)
  float* g     = (float*)d_ws;                       // N*256
  float* y     = g + (size_t)Nn * 256;               // N*256
  int*   nbr   = (int*)(y + (size_t)Nn * 256);       // N*4
  float* asrc  = (float*)(nbr + (size_t)Nn * 4);     // N*4
  float* adst  = asrc + (size_t)Nn * 4;              // N*4
  float* alpha = adst + (size_t)Nn * 4;              // N*16
  float* g2    = alpha + (size_t)Nn * 16;            // N*2
  float* s2    = g2 + (size_t)Nn * 2;                // N
  float* d2    = s2 + (size_t)Nn;                    // N

  knn_kernel<<<dim3(Pn / 256, Bn), 256, 0, stream>>>(coords, nbr);

  // Layer 0
  gemm_f32_256<<<dim3(2, Nn / 128), 256, 0, stream>>>(x, W0, g);
  attn_coeff_kernel<<<Nn / 4, 256, 0, stream>>>(g, as0, ad0, asrc, adst);
  alpha_kernel<<<Nn / 256, 256, 0, stream>>>(nbr, asrc, adst, alpha);
  aggregate_kernel<true><<<Nn / 4, 256, 0, stream>>>(g, nbr, alpha, b0, y);

  // Layer 1
  gemm_f32_256<<<dim3(2, Nn / 128), 256, 0, stream>>>(y, W1, g);
  attn_coeff_kernel<<<Nn / 4, 256, 0, stream>>>(g, as1, ad1, asrc, adst);
  alpha_kernel<<<Nn / 256, 256, 0, stream>>>(nbr, asrc, adst, alpha);
  aggregate_kernel<true><<<Nn / 4, 256, 0, stream>>>(g, nbr, alpha, b1, y);

  // Layer 2 (H=1, F=2) + final aggregation
  head2_kernel<<<Nn / 4, 256, 0, stream>>>(y, W2, as2, ad2, g2, s2, d2);
  final_kernel<<<Nn / 256, 256, 0, stream>>>(nbr, g2, s2, d2, b2, out);
}

// Round 3
// 1178.993 us; speedup vs baseline: 1.1746x; 1.1746x over previous
//
#include <hip/hip_runtime.h>
#include <math.h>

// Problem constants (B=16, P=8192)
constexpr int Bn = 16, Pn = 8192, Nn = 16 * 8192, Cc = 256;

// ---------------------------------------------------------------------------
// kNN: per batch, brute-force top-4 smallest squared distances (self incl.)
// Tie-break: strict '<' while scanning ascending j  == jax.lax.top_k stability.
// v2: 16 candidates per loop body (8x float4 LDS reads) for ILP; insertion
// branches are rarely taken (E[#updates] ~ 4*ln(P) per query).
// ---------------------------------------------------------------------------
__global__ __launch_bounds__(256) void knn_kernel(const float* __restrict__ coords,
                                                  int* __restrict__ nbr) {
  __shared__ float sxy[Pn * 2];  // 64 KB
  const int b = blockIdx.y;
  const int t = threadIdx.x;
  // cooperative load of the whole batch's coords (4096 float4)
  const float4* src = (const float4*)(coords + (size_t)b * Pn * 2);
  float4* dst = (float4*)sxy;
#pragma unroll
  for (int i = 0; i < 16; ++i) dst[t + i * 256] = src[t + i * 256];
  __syncthreads();

  const int qi = blockIdx.x * 256 + t;
  const float qx = sxy[qi * 2], qy = sxy[qi * 2 + 1];
  float d0 = 3.4e38f, d1 = 3.4e38f, d2 = 3.4e38f, d3 = 3.4e38f;
  int i0 = 0, i1 = 0, i2 = 0, i3 = 0;

  const float4* s4 = (const float4*)sxy;  // 4096 float4, 2 points each

#define KNN_INSERT(dd, jj)                                          \
  if (dd < d3) {                                                    \
    if (dd < d2) {                                                  \
      d3 = d2; i3 = i2;                                             \
      if (dd < d1) {                                                \
        d2 = d1; i2 = i1;                                           \
        if (dd < d0) { d1 = d0; i1 = i0; d0 = dd; i0 = jj; }        \
        else         { d1 = dd; i1 = jj; }                          \
      } else { d2 = dd; i2 = jj; }                                  \
    } else { d3 = dd; i3 = jj; }                                    \
  }

  for (int jb = 0; jb < Pn / 2; jb += 8) {  // 16 candidates per body
    float4 c[8];
#pragma unroll
    for (int u = 0; u < 8; ++u) c[u] = s4[jb + u];
    float dist[16];
#pragma unroll
    for (int u = 0; u < 8; ++u) {
      float dxa = qx - c[u].x, dya = qy - c[u].y;
      float dxb = qx - c[u].z, dyb = qy - c[u].w;
      // match XLA: dx*dx + dy*dy, no fma contraction
      dist[2 * u]     = __fadd_rn(__fmul_rn(dxa, dxa), __fmul_rn(dya, dya));
      dist[2 * u + 1] = __fadd_rn(__fmul_rn(dxb, dxb), __fmul_rn(dyb, dyb));
    }
#pragma unroll
    for (int u = 0; u < 16; ++u) {
      const int j = jb * 2 + u;
      KNN_INSERT(dist[u], j);
    }
  }
#undef KNN_INSERT

  const int base = b * Pn;
  int4 outv = make_int4(base + i0, base + i1, base + i2, base + i3);
  *(int4*)&nbr[(size_t)(base + qi) * 4] = outv;
}

// ---------------------------------------------------------------------------
// f32 GEMM: A[M,256] @ W[256,256] -> C[M,256]; BM=BN=128, BK=16, 256 thr, 8x8
// __launch_bounds__(256,4): cap VGPR at 128 for 4 waves/SIMD.
// ---------------------------------------------------------------------------
__global__ __launch_bounds__(256, 4) void gemm_f32_256(const float* __restrict__ A,
                                                       const float* __restrict__ W,
                                                       float* __restrict__ C) {
  __shared__ float As[16][132];  // A^T tile, padded
  __shared__ float Bs[16][128];
  const int tid = threadIdx.x;
  const int row0 = blockIdx.y * 128;
  const int col0 = blockIdx.x * 128;
  const int tm = tid & 15, tn = tid >> 4;

  float acc[8][8];
#pragma unroll
  for (int i = 0; i < 8; ++i)
#pragma unroll
    for (int j = 0; j < 8; ++j) acc[i][j] = 0.f;

  const int ar = tid >> 2;         // 0..63
  const int ac = (tid & 3) * 4;    // 0,4,8,12
  const int bk = tid >> 5;         // 0..7
  const int bn = (tid & 31) * 4;   // 0..124

  for (int kt = 0; kt < 16; ++kt) {
    const int k0 = kt * 16;
    float4 a0 = *(const float4*)&A[(size_t)(row0 + ar) * 256 + k0 + ac];
    float4 a1 = *(const float4*)&A[(size_t)(row0 + ar + 64) * 256 + k0 + ac];
    float4 b0 = *(const float4*)&W[(size_t)(k0 + bk) * 256 + col0 + bn];
    float4 b1 = *(const float4*)&W[(size_t)(k0 + bk + 8) * 256 + col0 + bn];
    __syncthreads();
    As[ac + 0][ar] = a0.x; As[ac + 1][ar] = a0.y;
    As[ac + 2][ar] = a0.z; As[ac + 3][ar] = a0.w;
    As[ac + 0][ar + 64] = a1.x; As[ac + 1][ar + 64] = a1.y;
    As[ac + 2][ar + 64] = a1.z; As[ac + 3][ar + 64] = a1.w;
    *(float4*)&Bs[bk][bn] = b0;
    *(float4*)&Bs[bk + 8][bn] = b1;
    __syncthreads();
#pragma unroll
    for (int kk = 0; kk < 16; ++kk) {
      float a[8], bb[8];
      *(float4*)&a[0] = *(const float4*)&As[kk][tm * 8];
      *(float4*)&a[4] = *(const float4*)&As[kk][tm * 8 + 4];
      *(float4*)&bb[0] = *(const float4*)&Bs[kk][tn * 8];
      *(float4*)&bb[4] = *(const float4*)&Bs[kk][tn * 8 + 4];
#pragma unroll
      for (int i = 0; i < 8; ++i)
#pragma unroll
        for (int j = 0; j < 8; ++j) acc[i][j] = fmaf(a[i], bb[j], acc[i][j]);
    }
  }
#pragma unroll
  for (int i = 0; i < 8; ++i) {
    const size_t r = (size_t)(row0 + tm * 8 + i);
    float4 c0 = make_float4(acc[i][0], acc[i][1], acc[i][2], acc[i][3]);
    float4 c1 = make_float4(acc[i][4], acc[i][5], acc[i][6], acc[i][7]);
    *(float4*)&C[r * 256 + col0 + tn * 8] = c0;
    *(float4*)&C[r * 256 + col0 + tn * 8 + 4] = c1;
  }
}

// ---------------------------------------------------------------------------
// asrc[n,h] = sum_f g[n, h*64+f] * att_src[h,f]; same for adst. One wave/node.
// ---------------------------------------------------------------------------
__global__ __launch_bounds__(256) void attn_coeff_kernel(const float* __restrict__ g,
                                                         const float* __restrict__ att_src,
                                                         const float* __restrict__ att_dst,
                                                         float* __restrict__ asrc,
                                                         float* __restrict__ adst) {
  const int t = threadIdx.x;
  const int lane = t & 63;
  const int n = blockIdx.x * 4 + (t >> 6);
  float4 v  = *(const float4*)&g[(size_t)n * 256 + lane * 4];
  float4 as = *(const float4*)&att_src[lane * 4];  // h*64 + (lane%16)*4 == lane*4
  float4 ad = *(const float4*)&att_dst[lane * 4];
  float ps = v.x * as.x + v.y * as.y + v.z * as.z + v.w * as.w;
  float pd = v.x * ad.x + v.y * ad.y + v.z * ad.z + v.w * ad.w;
#pragma unroll
  for (int off = 1; off < 16; off <<= 1) {
    ps += __shfl_xor(ps, off);
    pd += __shfl_xor(pd, off);
  }
  if ((lane & 15) == 0) {
    asrc[(size_t)n * 4 + (lane >> 4)] = ps;
    adst[(size_t)n * 4 + (lane >> 4)] = pd;
  }
}

__device__ __forceinline__ float leaky02(float x) { return x >= 0.f ? x : 0.2f * x; }

// ---------------------------------------------------------------------------
// alpha[n, j, h] = softmax_j leaky(asrc[nbr_j,h] + adst[n,h])   (H=4, k=4)
// ---------------------------------------------------------------------------
__global__ __launch_bounds__(256) void alpha_kernel(const int* __restrict__ nbr,
                                                    const float* __restrict__ asrc,
                                                    const float* __restrict__ adst,
                                                    float* __restrict__ alpha) {
  const int n = blockIdx.x * 256 + threadIdx.x;
  int4 nb = *(const int4*)&nbr[(size_t)n * 4];
  float4 ad = *(const float4*)&adst[(size_t)n * 4];
  int idx[4] = {nb.x, nb.y, nb.z, nb.w};
  float4 e[4];
#pragma unroll
  for (int j = 0; j < 4; ++j) {
    float4 as = *(const float4*)&asrc[(size_t)idx[j] * 4];
    e[j].x = leaky02(as.x + ad.x);
    e[j].y = leaky02(as.y + ad.y);
    e[j].z = leaky02(as.z + ad.z);
    e[j].w = leaky02(as.w + ad.w);
  }
  float4 m = e[0];
#pragma unroll
  for (int j = 1; j < 4; ++j) {
    m.x = fmaxf(m.x, e[j].x); m.y = fmaxf(m.y, e[j].y);
    m.z = fmaxf(m.z, e[j].z); m.w = fmaxf(m.w, e[j].w);
  }
  float4 s = make_float4(0.f, 0.f, 0.f, 0.f);
#pragma unroll
  for (int j = 0; j < 4; ++j) {
    e[j].x = expf(e[j].x - m.x); e[j].y = expf(e[j].y - m.y);
    e[j].z = expf(e[j].z - m.z); e[j].w = expf(e[j].w - m.w);
    s.x += e[j].x; s.y += e[j].y; s.z += e[j].z; s.w += e[j].w;
  }
#pragma unroll
  for (int j = 0; j < 4; ++j) {
    float4 o = make_float4(e[j].x / s.x, e[j].y / s.y, e[j].z / s.z, e[j].w / s.w);
    *(float4*)&alpha[(size_t)n * 16 + j * 4] = o;
  }
}

// ---------------------------------------------------------------------------
// out[n, h*64+f] = sum_j alpha[n,j,h] * g[nbr_j, h*64+f] + bias; optional ELU.
// One wave per node; lane owns 4 consecutive features.
// ---------------------------------------------------------------------------
template <bool ELU>
__global__ __launch_bounds__(256) void aggregate_kernel(const float* __restrict__ g,
                                                        const int* __restrict__ nbr,
                                                        const float* __restrict__ alpha,
                                                        const float* __restrict__ bias,
                                                        float* __restrict__ y) {
  const int t = threadIdx.x;
  const int lane = t & 63;
  const int n = blockIdx.x * 4 + (t >> 6);
  int4 nb = *(const int4*)&nbr[(size_t)n * 4];
  const int h = lane >> 4;
  const float a0 = alpha[(size_t)n * 16 + 0 + h];
  const float a1 = alpha[(size_t)n * 16 + 4 + h];
  const float a2 = alpha[(size_t)n * 16 + 8 + h];
  const float a3 = alpha[(size_t)n * 16 + 12 + h];
  const int c = lane * 4;
  float4 v0 = *(const float4*)&g[(size_t)nb.x * 256 + c];
  float4 v1 = *(const float4*)&g[(size_t)nb.y * 256 + c];
  float4 v2 = *(const float4*)&g[(size_t)nb.z * 256 + c];
  float4 v3 = *(const float4*)&g[(size_t)nb.w * 256 + c];
  float4 bb = *(const float4*)&bias[c];
  float4 o;
  o.x = a0 * v0.x + a1 * v1.x + a2 * v2.x + a3 * v3.x + bb.x;
  o.y = a0 * v0.y + a1 * v1.y + a2 * v2.y + a3 * v3.y + bb.y;
  o.z = a0 * v0.z + a1 * v1.z + a2 * v2.z + a3 * v3.z + bb.z;
  o.w = a0 * v0.w + a1 * v1.w + a2 * v2.w + a3 * v3.w + bb.w;
  if (ELU) {
    o.x = o.x > 0.f ? o.x : expm1f(o.x);
    o.y = o.y > 0.f ? o.y : expm1f(o.y);
    o.z = o.z > 0.f ? o.z : expm1f(o.z);
    o.w = o.w > 0.f ? o.w : expm1f(o.w);
  }
  *(float4*)&y[(size_t)n * 256 + c] = o;
}

// ---------------------------------------------------------------------------
// Layer 2 projection: g2[n,0..1] = y[n,:] @ W2[:,0..1]; also asrc2/adst2 scalars.
// One wave per node, full-wave reduction.
// ---------------------------------------------------------------------------
__global__ __launch_bounds__(256) void head2_kernel(const float* __restrict__ y,
                                                    const float* __restrict__ W2,
                                                    const float* __restrict__ as2,
                                                    const float* __restrict__ ad2,
                                                    float* __restrict__ g2,
                                                    float* __restrict__ asrc2,
                                                    float* __restrict__ adst2) {
  const int t = threadIdx.x, lane = t & 63;
  const int n = blockIdx.x * 4 + (t >> 6);
  float4 v  = *(const float4*)&y[(size_t)n * 256 + lane * 4];
  float4 wa = *(const float4*)&W2[lane * 8];      // rows 4l,4l+1 (cols 0,1 each)
  float4 wb = *(const float4*)&W2[lane * 8 + 4];  // rows 4l+2,4l+3
  float p0 = v.x * wa.x + v.y * wa.z + v.z * wb.x + v.w * wb.z;
  float p1 = v.x * wa.y + v.y * wa.w + v.z * wb.y + v.w * wb.w;
#pragma unroll
  for (int off = 1; off < 64; off <<= 1) {
    p0 += __shfl_xor(p0, off);
    p1 += __shfl_xor(p1, off);
  }
  if (lane == 0) {
    g2[(size_t)n * 2]     = p0;
    g2[(size_t)n * 2 + 1] = p1;
    asrc2[n] = p0 * as2[0] + p1 * as2[1];
    adst2[n] = p0 * ad2[0] + p1 * ad2[1];
  }
}

// ---------------------------------------------------------------------------
// Final aggregation (H=1, F=2) + bias -> d_out
// ---------------------------------------------------------------------------
__global__ __launch_bounds__(256) void final_kernel(const int* __restrict__ nbr,
                                                    const float* __restrict__ g2,
                                                    const float* __restrict__ asrc2,
                                                    const float* __restrict__ adst2,
                                                    const float* __restrict__ b2,
                                                    float* __restrict__ out) {
  const int n = blockIdx.x * 256 + threadIdx.x;
  int4 nb = *(const int4*)&nbr[(size_t)n * 4];
  const float ad = adst2[n];
  float e0 = leaky02(asrc2[nb.x] + ad);
  float e1 = leaky02(asrc2[nb.y] + ad);
  float e2 = leaky02(asrc2[nb.z] + ad);
  float e3 = leaky02(asrc2[nb.w] + ad);
  float m = fmaxf(fmaxf(e0, e1), fmaxf(e2, e3));
  float x0 = expf(e0 - m), x1 = expf(e1 - m), x2 = expf(e2 - m), x3 = expf(e3 - m);
  float s = x0 + x1 + x2 + x3;
  float o0 = (x0 * g2[(size_t)nb.x * 2] + x1 * g2[(size_t)nb.y * 2] +
              x2 * g2[(size_t)nb.z * 2] + x3 * g2[(size_t)nb.w * 2]) / s;
  float o1 = (x0 * g2[(size_t)nb.x * 2 + 1] + x1 * g2[(size_t)nb.y * 2 + 1] +
              x2 * g2[(size_t)nb.z * 2 + 1] + x3 * g2[(size_t)nb.w * 2 + 1]) / s;
  out[(size_t)n * 2]     = o0 + b2[0];
  out[(size_t)n * 2 + 1] = o1 + b2[1];
}

extern "C" void kernel_launch(void* const* d_in, const int* in_sizes, int n_in,
                              void* d_out, int out_size, void* d_ws, size_t ws_size,
                              hipStream_t stream) {
  const float* coords = (const float*)d_in[0];
  const float* x   = (const float*)d_in[1];
  const float* W0  = (const float*)d_in[2];
  const float* as0 = (const float*)d_in[3];
  const float* ad0 = (const float*)d_in[4];
  const float* b0  = (const float*)d_in[5];
  const float* W1  = (const float*)d_in[6];
  const float* as1 = (const float*)d_in[7];
  const float* ad1 = (const float*)d_in[8];
  const float* b1  = (const float*)d_in[9];
  const float* W2  = (const float*)d_in[10];
  const float* as2 = (const float*)d_in[11];
  const float* ad2 = (const float*)d_in[12];
  const float* b2  = (const float*)d_in[13];
  float* out = (float*)d_out;

  // workspace carve-up (~272 MiB)
  float* g     = (float*)d_ws;                       // N*256
  float* y     = g + (size_t)Nn * 256;               // N*256
  int*   nbr   = (int*)(y + (size_t)Nn * 256);       // N*4
  float* asrc  = (float*)(nbr + (size_t)Nn * 4);     // N*4
  float* adst  = asrc + (size_t)Nn * 4;              // N*4
  float* alpha = adst + (size_t)Nn * 4;              // N*16
  float* g2    = alpha + (size_t)Nn * 16;            // N*2
  float* s2    = g2 + (size_t)Nn * 2;                // N
  float* d2    = s2 + (size_t)Nn;                    // N

  knn_kernel<<<dim3(Pn / 256, Bn), 256, 0, stream>>>(coords, nbr);

  // Layer 0
  gemm_f32_256<<<dim3(2, Nn / 128), 256, 0, stream>>>(x, W0, g);
  attn_coeff_kernel<<<Nn / 4, 256, 0, stream>>>(g, as0, ad0, asrc, adst);
  alpha_kernel<<<Nn / 256, 256, 0, stream>>>(nbr, asrc, adst, alpha);
  aggregate_kernel<true><<<Nn / 4, 256, 0, stream>>>(g, nbr, alpha, b0, y);

  // Layer 1
  gemm_f32_256<<<dim3(2, Nn / 128), 256, 0, stream>>>(y, W1, g);
  attn_coeff_kernel<<<Nn / 4, 256, 0, stream>>>(g, as1, ad1, asrc, adst);
  alpha_kernel<<<Nn / 256, 256, 0, stream>>>(nbr, asrc, adst, alpha);
  aggregate_kernel<true><<<Nn / 4, 256, 0, stream>>>(g, nbr, alpha, b1, y);

  // Layer 2 (H=1, F=2) + final aggregation
  head2_kernel<<<Nn / 4, 256, 0, stream>>>(y, W2, as2, ad2, g2, s2, d2);
  final_kernel<<<Nn / 256, 256, 0, stream>>>(nbr, g2, s2, d2, b2, out);
}

// Round 4
// 1066.011 us; speedup vs baseline: 1.2990x; 1.1060x over previous
//
#include <hip/hip_runtime.h>
#include <math.h>

// Problem constants (B=16, P=8192)
constexpr int Bn = 16, Pn = 8192, Nn = 16 * 8192;

typedef __attribute__((ext_vector_type(8))) short short8;
typedef __attribute__((ext_vector_type(4))) float f32x4;

// f32 -> bf16 (round-to-nearest-even), and back
__device__ __forceinline__ unsigned short f2bf(float f) {
  unsigned u = __builtin_bit_cast(unsigned, f);
  unsigned r = (u + 0x7FFFu + ((u >> 16) & 1u)) >> 16;
  return (unsigned short)r;
}
__device__ __forceinline__ float bf2f(unsigned short h) {
  unsigned u = ((unsigned)h) << 16;
  return __builtin_bit_cast(float, u);
}

// ---------------------------------------------------------------------------
// kNN v3: candidate tiling (2048 pts = 16 KB LDS) for occupancy.
// Scan body identical to v2 (16 candidates, strict '<' == top_k stability).
// ---------------------------------------------------------------------------
constexpr int CT = 2048;  // candidates per LDS tile

__global__ __launch_bounds__(256) void knn_kernel(const float* __restrict__ coords,
                                                  int* __restrict__ nbr) {
  __shared__ float4 s4[CT / 2];  // 1024 float4 = 16 KB
  const int b = blockIdx.y;
  const int t = threadIdx.x;
  const int qi = blockIdx.x * 256 + t;
  const float2 q = ((const float2*)(coords + (size_t)b * Pn * 2))[qi];
  const float qx = q.x, qy = q.y;
  const float4* src = (const float4*)(coords + (size_t)b * Pn * 2);

  float d0 = 3.4e38f, d1 = 3.4e38f, d2 = 3.4e38f, d3 = 3.4e38f;
  int i0 = 0, i1 = 0, i2 = 0, i3 = 0;

#define KNN_INSERT(dd, jj)                                          \
  if (dd < d3) {                                                    \
    if (dd < d2) {                                                  \
      d3 = d2; i3 = i2;                                             \
      if (dd < d1) {                                                \
        d2 = d1; i2 = i1;                                           \
        if (dd < d0) { d1 = d0; i1 = i0; d0 = dd; i0 = jj; }        \
        else         { d1 = dd; i1 = jj; }                          \
      } else { d2 = dd; i2 = jj; }                                  \
    } else { d3 = dd; i3 = jj; }                                    \
  }

  for (int tile = 0; tile < Pn / CT; ++tile) {
    __syncthreads();  // previous tile's readers done
#pragma unroll
    for (int i = 0; i < 4; ++i) s4[t + i * 256] = src[tile * (CT / 2) + t + i * 256];
    __syncthreads();

    const int jbase = tile * CT;
    for (int jb = 0; jb < CT / 2; jb += 8) {  // 16 candidates per body
      float4 c[8];
#pragma unroll
      for (int u = 0; u < 8; ++u) c[u] = s4[jb + u];
      float dist[16];
#pragma unroll
      for (int u = 0; u < 8; ++u) {
        float dxa = qx - c[u].x, dya = qy - c[u].y;
        float dxb = qx - c[u].z, dyb = qy - c[u].w;
        // match XLA: dx*dx + dy*dy, no fma contraction
        dist[2 * u]     = __fadd_rn(__fmul_rn(dxa, dxa), __fmul_rn(dya, dya));
        dist[2 * u + 1] = __fadd_rn(__fmul_rn(dxb, dxb), __fmul_rn(dyb, dyb));
      }
#pragma unroll
      for (int u = 0; u < 16; ++u) {
        const int j = jbase + jb * 2 + u;
        KNN_INSERT(dist[u], j);
      }
    }
  }
#undef KNN_INSERT

  const int base = b * Pn;
  int4 outv = make_int4(base + i0, base + i1, base + i2, base + i3);
  *(int4*)&nbr[(size_t)(base + qi) * 4] = outv;
}

// ---------------------------------------------------------------------------
// W [256][256] f32 (row-major [k][n]) -> Wt_h/Wt_l bf16 [n][k] (transposed)
// ---------------------------------------------------------------------------
__global__ __launch_bounds__(256) void wt_kernel(const float* __restrict__ W,
                                                 unsigned short* __restrict__ Wth,
                                                 unsigned short* __restrict__ Wtl) {
  const int k = blockIdx.x, n = threadIdx.x;
  float v = W[k * 256 + n];
  unsigned short h = f2bf(v);
  unsigned short l = f2bf(v - bf2f(h));
  Wth[n * 256 + k] = h;
  Wtl[n * 256 + k] = l;
}

// ---------------------------------------------------------------------------
// bf16x3 MFMA GEMM: C[M,256] = A[M,256] @ W.  A converted hi/lo in-kernel;
// W pre-transposed+split (Wt_h/Wt_l [n][k]).  BM=128, BN=128, BK=32,
// 256 thr = 4 waves, each wave 64x64 via 4x4 mfma_16x16x32 frags, 3 passes
// (Ah*Bh + Ah*Bl + Al*Bh) into one f32 acc.
// ---------------------------------------------------------------------------
__global__ __launch_bounds__(256, 2) void gemm_bf3(const float* __restrict__ A,
                                                   const unsigned short* __restrict__ Bth,
                                                   const unsigned short* __restrict__ Btl,
                                                   float* __restrict__ C) {
  __shared__ unsigned short Ah[128][40], Al[128][40];  // +8 pad: bank-friendly
  __shared__ unsigned short Bh[128][40], Bl[128][40];
  const int t = threadIdx.x;
  const int row0 = blockIdx.y * 128;
  const int col0 = blockIdx.x * 128;
  const int wid = t >> 6, lane = t & 63;
  const int wr = (wid >> 1) * 64, wc = (wid & 1) * 64;
  const int lrow = lane & 15, lko = (lane >> 4) * 8;

  f32x4 acc[4][4];
#pragma unroll
  for (int i = 0; i < 4; ++i)
#pragma unroll
    for (int j = 0; j < 4; ++j) acc[i][j] = {0.f, 0.f, 0.f, 0.f};

  for (int kt = 0; kt < 8; ++kt) {
    const int k0 = kt * 32;
    // --- global loads to regs (before barrier) ---
    float4 av[4];
#pragma unroll
    for (int i = 0; i < 4; ++i) {
      const int idx = t + i * 256;           // 0..1023
      const int row = idx >> 3, kq = idx & 7;
      av[i] = *(const float4*)&A[(size_t)(row0 + row) * 256 + k0 + kq * 4];
    }
    uint4 bh[2], bl[2];
#pragma unroll
    for (int i = 0; i < 2; ++i) {
      const int idx = t + i * 256;           // 0..511
      const int col = idx >> 2, kc = idx & 3;
      bh[i] = *(const uint4*)&Bth[(size_t)(col0 + col) * 256 + k0 + kc * 8];
      bl[i] = *(const uint4*)&Btl[(size_t)(col0 + col) * 256 + k0 + kc * 8];
    }
    __syncthreads();  // previous iter's frag reads done
    // --- convert A and stage LDS ---
#pragma unroll
    for (int i = 0; i < 4; ++i) {
      const int idx = t + i * 256;
      const int row = idx >> 3, kq = idx & 7;
      const float vv[4] = {av[i].x, av[i].y, av[i].z, av[i].w};
      unsigned short hh[4], ll[4];
#pragma unroll
      for (int e = 0; e < 4; ++e) {
        hh[e] = f2bf(vv[e]);
        ll[e] = f2bf(vv[e] - bf2f(hh[e]));
      }
      *(ushort4*)&Ah[row][kq * 4] = make_ushort4(hh[0], hh[1], hh[2], hh[3]);
      *(ushort4*)&Al[row][kq * 4] = make_ushort4(ll[0], ll[1], ll[2], ll[3]);
    }
#pragma unroll
    for (int i = 0; i < 2; ++i) {
      const int idx = t + i * 256;
      const int col = idx >> 2, kc = idx & 3;
      *(uint4*)&Bh[col][kc * 8] = bh[i];
      *(uint4*)&Bl[col][kc * 8] = bl[i];
    }
    __syncthreads();
    // --- fragments + MFMA ---
    short8 afh[4], afl[4], bfh[4], bfl[4];
#pragma unroll
    for (int f = 0; f < 4; ++f) {
      afh[f] = *(const short8*)&Ah[wr + f * 16 + lrow][lko];
      afl[f] = *(const short8*)&Al[wr + f * 16 + lrow][lko];
      bfh[f] = *(const short8*)&Bh[wc + f * 16 + lrow][lko];
      bfl[f] = *(const short8*)&Bl[wc + f * 16 + lrow][lko];
    }
#pragma unroll
    for (int fr = 0; fr < 4; ++fr)
#pragma unroll
      for (int fc = 0; fc < 4; ++fc) {
        acc[fr][fc] = __builtin_amdgcn_mfma_f32_16x16x32_bf16(afh[fr], bfh[fc], acc[fr][fc], 0, 0, 0);
        acc[fr][fc] = __builtin_amdgcn_mfma_f32_16x16x32_bf16(afh[fr], bfl[fc], acc[fr][fc], 0, 0, 0);
        acc[fr][fc] = __builtin_amdgcn_mfma_f32_16x16x32_bf16(afl[fr], bfh[fc], acc[fr][fc], 0, 0, 0);
      }
  }
  // --- epilogue: C/D layout col=lane&15, row=(lane>>4)*4+j (m89) ---
#pragma unroll
  for (int fr = 0; fr < 4; ++fr)
#pragma unroll
    for (int fc = 0; fc < 4; ++fc) {
      const int col = col0 + wc + fc * 16 + (lane & 15);
#pragma unroll
      for (int j = 0; j < 4; ++j) {
        const int row = row0 + wr + fr * 16 + (lane >> 4) * 4 + j;
        C[(size_t)row * 256 + col] = acc[fr][fc][j];
      }
    }
}

// ---------------------------------------------------------------------------
// asrc[n,h] = sum_f g[n, h*64+f] * att_src[h,f]; same for adst. 16 lanes/node.
// ---------------------------------------------------------------------------
__global__ __launch_bounds__(256) void attn_coeff_kernel(const float* __restrict__ g,
                                                         const float* __restrict__ att_src,
                                                         const float* __restrict__ att_dst,
                                                         float* __restrict__ asrc,
                                                         float* __restrict__ adst) {
  const int t = threadIdx.x;
  const int lane = t & 63;
  const int n = blockIdx.x * 4 + (t >> 6);
  float4 v  = *(const float4*)&g[(size_t)n * 256 + lane * 4];
  float4 as = *(const float4*)&att_src[lane * 4];  // h*64 + (lane%16)*4 == lane*4
  float4 ad = *(const float4*)&att_dst[lane * 4];
  float ps = v.x * as.x + v.y * as.y + v.z * as.z + v.w * as.w;
  float pd = v.x * ad.x + v.y * ad.y + v.z * ad.z + v.w * ad.w;
#pragma unroll
  for (int off = 1; off < 16; off <<= 1) {
    ps += __shfl_xor(ps, off);
    pd += __shfl_xor(pd, off);
  }
  if ((lane & 15) == 0) {
    asrc[(size_t)n * 4 + (lane >> 4)] = ps;
    adst[(size_t)n * 4 + (lane >> 4)] = pd;
  }
}

__device__ __forceinline__ float leaky02(float x) { return x >= 0.f ? x : 0.2f * x; }

// ---------------------------------------------------------------------------
// alpha[n, j, h] = softmax_j leaky(asrc[nbr_j,h] + adst[n,h])   (H=4, k=4)
// ---------------------------------------------------------------------------
__global__ __launch_bounds__(256) void alpha_kernel(const int* __restrict__ nbr,
                                                    const float* __restrict__ asrc,
                                                    const float* __restrict__ adst,
                                                    float* __restrict__ alpha) {
  const int n = blockIdx.x * 256 + threadIdx.x;
  int4 nb = *(const int4*)&nbr[(size_t)n * 4];
  float4 ad = *(const float4*)&adst[(size_t)n * 4];
  int idx[4] = {nb.x, nb.y, nb.z, nb.w};
  float4 e[4];
#pragma unroll
  for (int j = 0; j < 4; ++j) {
    float4 as = *(const float4*)&asrc[(size_t)idx[j] * 4];
    e[j].x = leaky02(as.x + ad.x);
    e[j].y = leaky02(as.y + ad.y);
    e[j].z = leaky02(as.z + ad.z);
    e[j].w = leaky02(as.w + ad.w);
  }
  float4 m = e[0];
#pragma unroll
  for (int j = 1; j < 4; ++j) {
    m.x = fmaxf(m.x, e[j].x); m.y = fmaxf(m.y, e[j].y);
    m.z = fmaxf(m.z, e[j].z); m.w = fmaxf(m.w, e[j].w);
  }
  float4 s = make_float4(0.f, 0.f, 0.f, 0.f);
#pragma unroll
  for (int j = 0; j < 4; ++j) {
    e[j].x = expf(e[j].x - m.x); e[j].y = expf(e[j].y - m.y);
    e[j].z = expf(e[j].z - m.z); e[j].w = expf(e[j].w - m.w);
    s.x += e[j].x; s.y += e[j].y; s.z += e[j].z; s.w += e[j].w;
  }
#pragma unroll
  for (int j = 0; j < 4; ++j) {
    float4 o = make_float4(e[j].x / s.x, e[j].y / s.y, e[j].z / s.z, e[j].w / s.w);
    *(float4*)&alpha[(size_t)n * 16 + j * 4] = o;
  }
}

// ---------------------------------------------------------------------------
// out[n, h*64+f] = sum_j alpha[n,j,h] * g[nbr_j, h*64+f] + bias; optional ELU.
// ---------------------------------------------------------------------------
template <bool ELU>
__global__ __launch_bounds__(256) void aggregate_kernel(const float* __restrict__ g,
                                                        const int* __restrict__ nbr,
                                                        const float* __restrict__ alpha,
                                                        const float* __restrict__ bias,
                                                        float* __restrict__ y) {
  const int t = threadIdx.x;
  const int lane = t & 63;
  const int n = blockIdx.x * 4 + (t >> 6);
  int4 nb = *(const int4*)&nbr[(size_t)n * 4];
  const int h = lane >> 4;
  const float a0 = alpha[(size_t)n * 16 + 0 + h];
  const float a1 = alpha[(size_t)n * 16 + 4 + h];
  const float a2 = alpha[(size_t)n * 16 + 8 + h];
  const float a3 = alpha[(size_t)n * 16 + 12 + h];
  const int c = lane * 4;
  float4 v0 = *(const float4*)&g[(size_t)nb.x * 256 + c];
  float4 v1 = *(const float4*)&g[(size_t)nb.y * 256 + c];
  float4 v2 = *(const float4*)&g[(size_t)nb.z * 256 + c];
  float4 v3 = *(const float4*)&g[(size_t)nb.w * 256 + c];
  float4 bb = *(const float4*)&bias[c];
  float4 o;
  o.x = a0 * v0.x + a1 * v1.x + a2 * v2.x + a3 * v3.x + bb.x;
  o.y = a0 * v0.y + a1 * v1.y + a2 * v2.y + a3 * v3.y + bb.y;
  o.z = a0 * v0.z + a1 * v1.z + a2 * v2.z + a3 * v3.z + bb.z;
  o.w = a0 * v0.w + a1 * v1.w + a2 * v2.w + a3 * v3.w + bb.w;
  if (ELU) {
    o.x = o.x > 0.f ? o.x : expm1f(o.x);
    o.y = o.y > 0.f ? o.y : expm1f(o.y);
    o.z = o.z > 0.f ? o.z : expm1f(o.z);
    o.w = o.w > 0.f ? o.w : expm1f(o.w);
  }
  *(float4*)&y[(size_t)n * 256 + c] = o;
}

// ---------------------------------------------------------------------------
// Layer 2 projection: g2[n,0..1] = y[n,:] @ W2[:,0..1]; also asrc2/adst2.
// ---------------------------------------------------------------------------
__global__ __launch_bounds__(256) void head2_kernel(const float* __restrict__ y,
                                                    const float* __restrict__ W2,
                                                    const float* __restrict__ as2,
                                                    const float* __restrict__ ad2,
                                                    float* __restrict__ g2,
                                                    float* __restrict__ asrc2,
                                                    float* __restrict__ adst2) {
  const int t = threadIdx.x, lane = t & 63;
  const int n = blockIdx.x * 4 + (t >> 6);
  float4 v  = *(const float4*)&y[(size_t)n * 256 + lane * 4];
  float4 wa = *(const float4*)&W2[lane * 8];      // rows 4l,4l+1 (cols 0,1 each)
  float4 wb = *(const float4*)&W2[lane * 8 + 4];  // rows 4l+2,4l+3
  float p0 = v.x * wa.x + v.y * wa.z + v.z * wb.x + v.w * wb.z;
  float p1 = v.x * wa.y + v.y * wa.w + v.z * wb.y + v.w * wb.w;
#pragma unroll
  for (int off = 1; off < 64; off <<= 1) {
    p0 += __shfl_xor(p0, off);
    p1 += __shfl_xor(p1, off);
  }
  if (lane == 0) {
    g2[(size_t)n * 2]     = p0;
    g2[(size_t)n * 2 + 1] = p1;
    asrc2[n] = p0 * as2[0] + p1 * as2[1];
    adst2[n] = p0 * ad2[0] + p1 * ad2[1];
  }
}

// ---------------------------------------------------------------------------
// Final aggregation (H=1, F=2) + bias -> d_out
// ---------------------------------------------------------------------------
__global__ __launch_bounds__(256) void final_kernel(const int* __restrict__ nbr,
                                                    const float* __restrict__ g2,
                                                    const float* __restrict__ asrc2,
                                                    const float* __restrict__ adst2,
                                                    const float* __restrict__ b2,
                                                    float* __restrict__ out) {
  const int n = blockIdx.x * 256 + threadIdx.x;
  int4 nb = *(const int4*)&nbr[(size_t)n * 4];
  const float ad = adst2[n];
  float e0 = leaky02(asrc2[nb.x] + ad);
  float e1 = leaky02(asrc2[nb.y] + ad);
  float e2 = leaky02(asrc2[nb.z] + ad);
  float e3 = leaky02(asrc2[nb.w] + ad);
  float m = fmaxf(fmaxf(e0, e1), fmaxf(e2, e3));
  float x0 = expf(e0 - m), x1 = expf(e1 - m), x2 = expf(e2 - m), x3 = expf(e3 - m);
  float s = x0 + x1 + x2 + x3;
  float o0 = (x0 * g2[(size_t)nb.x * 2] + x1 * g2[(size_t)nb.y * 2] +
              x2 * g2[(size_t)nb.z * 2] + x3 * g2[(size_t)nb.w * 2]) / s;
  float o1 = (x0 * g2[(size_t)nb.x * 2 + 1] + x1 * g2[(size_t)nb.y * 2 + 1] +
              x2 * g2[(size_t)nb.z * 2 + 1] + x3 * g2[(size_t)nb.w * 2 + 1]) / s;
  out[(size_t)n * 2]     = o0 + b2[0];
  out[(size_t)n * 2 + 1] = o1 + b2[1];
}

extern "C" void kernel_launch(void* const* d_in, const int* in_sizes, int n_in,
                              void* d_out, int out_size, void* d_ws, size_t ws_size,
                              hipStream_t stream) {
  const float* coords = (const float*)d_in[0];
  const float* x   = (const float*)d_in[1];
  const float* W0  = (const float*)d_in[2];
  const float* as0 = (const float*)d_in[3];
  const float* ad0 = (const float*)d_in[4];
  const float* b0  = (const float*)d_in[5];
  const float* W1  = (const float*)d_in[6];
  const float* as1 = (const float*)d_in[7];
  const float* ad1 = (const float*)d_in[8];
  const float* b1  = (const float*)d_in[9];
  const float* W2  = (const float*)d_in[10];
  const float* as2 = (const float*)d_in[11];
  const float* ad2 = (const float*)d_in[12];
  const float* b2  = (const float*)d_in[13];
  float* out = (float*)d_out;

  // workspace carve-up (~273 MiB)
  float* g     = (float*)d_ws;                       // N*256
  float* y     = g + (size_t)Nn * 256;               // N*256
  int*   nbr   = (int*)(y + (size_t)Nn * 256);       // N*4
  float* asrc  = (float*)(nbr + (size_t)Nn * 4);     // N*4
  float* adst  = asrc + (size_t)Nn * 4;              // N*4
  float* alpha = adst + (size_t)Nn * 4;              // N*16
  float* g2    = alpha + (size_t)Nn * 16;            // N*2
  float* s2    = g2 + (size_t)Nn * 2;                // N
  float* d2    = s2 + (size_t)Nn;                    // N
  unsigned short* Wth = (unsigned short*)(d2 + (size_t)Nn);  // 256*256
  unsigned short* Wtl = Wth + 256 * 256;                     // 256*256

  knn_kernel<<<dim3(Pn / 256, Bn), 256, 0, stream>>>(coords, nbr);

  // Layer 0
  wt_kernel<<<256, 256, 0, stream>>>(W0, Wth, Wtl);
  gemm_bf3<<<dim3(2, Nn / 128), 256, 0, stream>>>(x, Wth, Wtl, g);
  attn_coeff_kernel<<<Nn / 4, 256, 0, stream>>>(g, as0, ad0, asrc, adst);
  alpha_kernel<<<Nn / 256, 256, 0, stream>>>(nbr, asrc, adst, alpha);
  aggregate_kernel<true><<<Nn / 4, 256, 0, stream>>>(g, nbr, alpha, b0, y);

  // Layer 1
  wt_kernel<<<256, 256, 0, stream>>>(W1, Wth, Wtl);
  gemm_bf3<<<dim3(2, Nn / 128), 256, 0, stream>>>(y, Wth, Wtl, g);
  attn_coeff_kernel<<<Nn / 4, 256, 0, stream>>>(g, as1, ad1, asrc, adst);
  alpha_kernel<<<Nn / 256, 256, 0, stream>>>(nbr, asrc, adst, alpha);
  aggregate_kernel<true><<<Nn / 4, 256, 0, stream>>>(g, nbr, alpha, b1, y);

  // Layer 2 (H=1, F=2) + final aggregation
  head2_kernel<<<Nn / 4, 256, 0, stream>>>(y, W2, as2, ad2, g2, s2, d2);
  final_kernel<<<Nn / 256, 256, 0, stream>>>(nbr, g2, s2, d2, b2, out);
}

// Round 5
// 1000.700 us; speedup vs baseline: 1.3838x; 1.0653x over previous
//
#include <hip/hip_runtime.h>
#include <math.h>

// Problem constants (B=16, P=8192)
constexpr int Bn = 16, Pn = 8192, Nn = 16 * 8192;

typedef __attribute__((ext_vector_type(8))) short short8;
typedef __attribute__((ext_vector_type(4))) float f32x4;

// f32 -> bf16 (round-to-nearest-even), and back
__device__ __forceinline__ unsigned short f2bf(float f) {
  unsigned u = __builtin_bit_cast(unsigned, f);
  unsigned r = (u + 0x7FFFu + ((u >> 16) & 1u)) >> 16;
  return (unsigned short)r;
}
__device__ __forceinline__ float bf2f(unsigned short h) {
  unsigned u = ((unsigned)h) << 16;
  return __builtin_bit_cast(float, u);
}

// ---------------------------------------------------------------------------
// kNN v4: candidate-chunk split for occupancy (grid was the limiter: 512
// blocks = 2 blocks/CU = 23% occ). Each block scans ONE 2048-candidate chunk
// (16 KB LDS); grid = 32 x 4 x 16 = 2048 blocks = 8 blocks/CU. Partial top-4
// per chunk -> merge kernel selects global top-4 by lexicographic (d, idx),
// which equals lax.top_k stable-tie semantics. min16 early-out skips the
// insertion checks for bodies that cannot update (strict '<' semantics).
// ---------------------------------------------------------------------------
constexpr int NCH = 4;          // candidate chunks per batch
constexpr int CT = Pn / NCH;    // 2048 candidates per chunk

__global__ __launch_bounds__(256) void knn_partial(const float* __restrict__ coords,
                                                   float* __restrict__ pd,
                                                   int* __restrict__ pi) {
  __shared__ float4 s4[CT / 2];  // 1024 float4 = 16 KB
  const int b = blockIdx.z;
  const int ch = blockIdx.y;
  const int t = threadIdx.x;
  const int qi = blockIdx.x * 256 + t;
  const float2 q = ((const float2*)(coords + (size_t)b * Pn * 2))[qi];
  const float qx = q.x, qy = q.y;
  const float4* src = (const float4*)(coords + (size_t)b * Pn * 2);
#pragma unroll
  for (int i = 0; i < 4; ++i) s4[t + i * 256] = src[ch * (CT / 2) + t + i * 256];
  __syncthreads();

  float d0 = 3.4e38f, d1 = 3.4e38f, d2 = 3.4e38f, d3 = 3.4e38f;
  int i0 = 0, i1 = 0, i2 = 0, i3 = 0;

#define KNN_INSERT(dd, jj)                                          \
  if (dd < d3) {                                                    \
    if (dd < d2) {                                                  \
      d3 = d2; i3 = i2;                                             \
      if (dd < d1) {                                                \
        d2 = d1; i2 = i1;                                           \
        if (dd < d0) { d1 = d0; i1 = i0; d0 = dd; i0 = jj; }        \
        else         { d1 = dd; i1 = jj; }                          \
      } else { d2 = dd; i2 = jj; }                                  \
    } else { d3 = dd; i3 = jj; }                                    \
  }

  const int jbase = ch * CT;
  for (int jb = 0; jb < CT / 2; jb += 8) {  // 16 candidates per body
    float4 c[8];
#pragma unroll
    for (int u = 0; u < 8; ++u) c[u] = s4[jb + u];
    float dist[16];
#pragma unroll
    for (int u = 0; u < 8; ++u) {
      float dxa = qx - c[u].x, dya = qy - c[u].y;
      float dxb = qx - c[u].z, dyb = qy - c[u].w;
      // match XLA: dx*dx + dy*dy, no fma contraction
      dist[2 * u]     = __fadd_rn(__fmul_rn(dxa, dxa), __fmul_rn(dya, dya));
      dist[2 * u + 1] = __fadd_rn(__fmul_rn(dxb, dxb), __fmul_rn(dyb, dyb));
    }
    // min16 tree: skip insertion checks unless something can beat d3
    float m01 = fminf(dist[0], dist[1]),  m23 = fminf(dist[2], dist[3]);
    float m45 = fminf(dist[4], dist[5]),  m67 = fminf(dist[6], dist[7]);
    float m89 = fminf(dist[8], dist[9]),  mab = fminf(dist[10], dist[11]);
    float mcd = fminf(dist[12], dist[13]), mef = fminf(dist[14], dist[15]);
    float ma = fminf(fminf(m01, m23), fminf(m45, m67));
    float mb = fminf(fminf(m89, mab), fminf(mcd, mef));
    if (fminf(ma, mb) < d3) {
#pragma unroll
      for (int u = 0; u < 16; ++u) {
        const int j = jbase + jb * 2 + u;
        KNN_INSERT(dist[u], j);
      }
    }
  }
#undef KNN_INSERT

  const size_t qg = (size_t)b * Pn + qi;          // global query id
  *(float4*)&pd[qg * 16 + ch * 4] = make_float4(d0, d1, d2, d3);
  *(int4*)&pi[qg * 16 + ch * 4]   = make_int4(i0, i1, i2, i3);
}

// Merge 4 partial top-4 lists -> global top-4 by (d, idx) lexicographic.
__global__ __launch_bounds__(256) void knn_merge(const float* __restrict__ pd,
                                                 const int* __restrict__ pi,
                                                 int* __restrict__ nbr) {
  const int q = blockIdx.x * 256 + threadIdx.x;
  const int b = q >> 13;  // / Pn
  float d[16];
  int ix[16];
#pragma unroll
  for (int c = 0; c < 4; ++c) {
    float4 dv = *(const float4*)&pd[(size_t)q * 16 + c * 4];
    int4 iv = *(const int4*)&pi[(size_t)q * 16 + c * 4];
    d[c * 4 + 0] = dv.x; d[c * 4 + 1] = dv.y; d[c * 4 + 2] = dv.z; d[c * 4 + 3] = dv.w;
    ix[c * 4 + 0] = iv.x; ix[c * 4 + 1] = iv.y; ix[c * 4 + 2] = iv.z; ix[c * 4 + 3] = iv.w;
  }
  int out[4];
#pragma unroll
  for (int s = 0; s < 4; ++s) {
    int best = 0;
#pragma unroll
    for (int u = 1; u < 16; ++u) {
      if (d[u] < d[best] || (d[u] == d[best] && ix[u] < ix[best])) best = u;
    }
    out[s] = ix[best];
    d[best] = 3.5e38f;
    ix[best] = 0x7fffffff;
  }
  const int base = b * Pn;
  *(int4*)&nbr[(size_t)q * 4] =
      make_int4(base + out[0], base + out[1], base + out[2], base + out[3]);
}

// ---------------------------------------------------------------------------
// W [256][256] f32 (row-major [k][n]) -> Wt_h/Wt_l bf16 [n][k] (transposed)
// ---------------------------------------------------------------------------
__global__ __launch_bounds__(256) void wt_kernel(const float* __restrict__ W,
                                                 unsigned short* __restrict__ Wth,
                                                 unsigned short* __restrict__ Wtl) {
  const int k = blockIdx.x, n = threadIdx.x;
  float v = W[k * 256 + n];
  unsigned short h = f2bf(v);
  unsigned short l = f2bf(v - bf2f(h));
  Wth[n * 256 + k] = h;
  Wtl[n * 256 + k] = l;
}

// ---------------------------------------------------------------------------
// bf16x3 MFMA GEMM: C[M,256] = A[M,256] @ W.  A converted hi/lo in-kernel;
// W pre-transposed+split (Wt_h/Wt_l [n][k]).  BM=128, BN=128, BK=32,
// 256 thr = 4 waves, each wave 64x64 via 4x4 mfma_16x16x32 frags, 3 passes
// (Ah*Bh + Ah*Bl + Al*Bh) into one f32 acc.
// ---------------------------------------------------------------------------
__global__ __launch_bounds__(256, 2) void gemm_bf3(const float* __restrict__ A,
                                                   const unsigned short* __restrict__ Bth,
                                                   const unsigned short* __restrict__ Btl,
                                                   float* __restrict__ C) {
  __shared__ unsigned short Ah[128][40], Al[128][40];  // +8 pad: bank-friendly
  __shared__ unsigned short Bh[128][40], Bl[128][40];
  const int t = threadIdx.x;
  const int row0 = blockIdx.y * 128;
  const int col0 = blockIdx.x * 128;
  const int wid = t >> 6, lane = t & 63;
  const int wr = (wid >> 1) * 64, wc = (wid & 1) * 64;
  const int lrow = lane & 15, lko = (lane >> 4) * 8;

  f32x4 acc[4][4];
#pragma unroll
  for (int i = 0; i < 4; ++i)
#pragma unroll
    for (int j = 0; j < 4; ++j) acc[i][j] = {0.f, 0.f, 0.f, 0.f};

  for (int kt = 0; kt < 8; ++kt) {
    const int k0 = kt * 32;
    // --- global loads to regs (before barrier) ---
    float4 av[4];
#pragma unroll
    for (int i = 0; i < 4; ++i) {
      const int idx = t + i * 256;           // 0..1023
      const int row = idx >> 3, kq = idx & 7;
      av[i] = *(const float4*)&A[(size_t)(row0 + row) * 256 + k0 + kq * 4];
    }
    uint4 bh[2], bl[2];
#pragma unroll
    for (int i = 0; i < 2; ++i) {
      const int idx = t + i * 256;           // 0..511
      const int col = idx >> 2, kc = idx & 3;
      bh[i] = *(const uint4*)&Bth[(size_t)(col0 + col) * 256 + k0 + kc * 8];
      bl[i] = *(const uint4*)&Btl[(size_t)(col0 + col) * 256 + k0 + kc * 8];
    }
    __syncthreads();  // previous iter's frag reads done
    // --- convert A and stage LDS ---
#pragma unroll
    for (int i = 0; i < 4; ++i) {
      const int idx = t + i * 256;
      const int row = idx >> 3, kq = idx & 7;
      const float vv[4] = {av[i].x, av[i].y, av[i].z, av[i].w};
      unsigned short hh[4], ll[4];
#pragma unroll
      for (int e = 0; e < 4; ++e) {
        hh[e] = f2bf(vv[e]);
        ll[e] = f2bf(vv[e] - bf2f(hh[e]));
      }
      *(ushort4*)&Ah[row][kq * 4] = make_ushort4(hh[0], hh[1], hh[2], hh[3]);
      *(ushort4*)&Al[row][kq * 4] = make_ushort4(ll[0], ll[1], ll[2], ll[3]);
    }
#pragma unroll
    for (int i = 0; i < 2; ++i) {
      const int idx = t + i * 256;
      const int col = idx >> 2, kc = idx & 3;
      *(uint4*)&Bh[col][kc * 8] = bh[i];
      *(uint4*)&Bl[col][kc * 8] = bl[i];
    }
    __syncthreads();
    // --- fragments + MFMA ---
    short8 afh[4], afl[4], bfh[4], bfl[4];
#pragma unroll
    for (int f = 0; f < 4; ++f) {
      afh[f] = *(const short8*)&Ah[wr + f * 16 + lrow][lko];
      afl[f] = *(const short8*)&Al[wr + f * 16 + lrow][lko];
      bfh[f] = *(const short8*)&Bh[wc + f * 16 + lrow][lko];
      bfl[f] = *(const short8*)&Bl[wc + f * 16 + lrow][lko];
    }
#pragma unroll
    for (int fr = 0; fr < 4; ++fr)
#pragma unroll
      for (int fc = 0; fc < 4; ++fc) {
        acc[fr][fc] = __builtin_amdgcn_mfma_f32_16x16x32_bf16(afh[fr], bfh[fc], acc[fr][fc], 0, 0, 0);
        acc[fr][fc] = __builtin_amdgcn_mfma_f32_16x16x32_bf16(afh[fr], bfl[fc], acc[fr][fc], 0, 0, 0);
        acc[fr][fc] = __builtin_amdgcn_mfma_f32_16x16x32_bf16(afl[fr], bfh[fc], acc[fr][fc], 0, 0, 0);
      }
  }
  // --- epilogue: C/D layout col=lane&15, row=(lane>>4)*4+j (m89) ---
#pragma unroll
  for (int fr = 0; fr < 4; ++fr)
#pragma unroll
    for (int fc = 0; fc < 4; ++fc) {
      const int col = col0 + wc + fc * 16 + (lane & 15);
#pragma unroll
      for (int j = 0; j < 4; ++j) {
        const int row = row0 + wr + fr * 16 + (lane >> 4) * 4 + j;
        C[(size_t)row * 256 + col] = acc[fr][fc][j];
      }
    }
}

// ---------------------------------------------------------------------------
// asrc[n,h] = sum_f g[n, h*64+f] * att_src[h,f]; same for adst. 16 lanes/node.
// ---------------------------------------------------------------------------
__global__ __launch_bounds__(256) void attn_coeff_kernel(const float* __restrict__ g,
                                                         const float* __restrict__ att_src,
                                                         const float* __restrict__ att_dst,
                                                         float* __restrict__ asrc,
                                                         float* __restrict__ adst) {
  const int t = threadIdx.x;
  const int lane = t & 63;
  const int n = blockIdx.x * 4 + (t >> 6);
  float4 v  = *(const float4*)&g[(size_t)n * 256 + lane * 4];
  float4 as = *(const float4*)&att_src[lane * 4];  // h*64 + (lane%16)*4 == lane*4
  float4 ad = *(const float4*)&att_dst[lane * 4];
  float ps = v.x * as.x + v.y * as.y + v.z * as.z + v.w * as.w;
  float pd = v.x * ad.x + v.y * ad.y + v.z * ad.z + v.w * ad.w;
#pragma unroll
  for (int off = 1; off < 16; off <<= 1) {
    ps += __shfl_xor(ps, off);
    pd += __shfl_xor(pd, off);
  }
  if ((lane & 15) == 0) {
    asrc[(size_t)n * 4 + (lane >> 4)] = ps;
    adst[(size_t)n * 4 + (lane >> 4)] = pd;
  }
}

__device__ __forceinline__ float leaky02(float x) { return x >= 0.f ? x : 0.2f * x; }

// ---------------------------------------------------------------------------
// alpha[n, j, h] = softmax_j leaky(asrc[nbr_j,h] + adst[n,h])   (H=4, k=4)
// ---------------------------------------------------------------------------
__global__ __launch_bounds__(256) void alpha_kernel(const int* __restrict__ nbr,
                                                    const float* __restrict__ asrc,
                                                    const float* __restrict__ adst,
                                                    float* __restrict__ alpha) {
  const int n = blockIdx.x * 256 + threadIdx.x;
  int4 nb = *(const int4*)&nbr[(size_t)n * 4];
  float4 ad = *(const float4*)&adst[(size_t)n * 4];
  int idx[4] = {nb.x, nb.y, nb.z, nb.w};
  float4 e[4];
#pragma unroll
  for (int j = 0; j < 4; ++j) {
    float4 as = *(const float4*)&asrc[(size_t)idx[j] * 4];
    e[j].x = leaky02(as.x + ad.x);
    e[j].y = leaky02(as.y + ad.y);
    e[j].z = leaky02(as.z + ad.z);
    e[j].w = leaky02(as.w + ad.w);
  }
  float4 m = e[0];
#pragma unroll
  for (int j = 1; j < 4; ++j) {
    m.x = fmaxf(m.x, e[j].x); m.y = fmaxf(m.y, e[j].y);
    m.z = fmaxf(m.z, e[j].z); m.w = fmaxf(m.w, e[j].w);
  }
  float4 s = make_float4(0.f, 0.f, 0.f, 0.f);
#pragma unroll
  for (int j = 0; j < 4; ++j) {
    e[j].x = expf(e[j].x - m.x); e[j].y = expf(e[j].y - m.y);
    e[j].z = expf(e[j].z - m.z); e[j].w = expf(e[j].w - m.w);
    s.x += e[j].x; s.y += e[j].y; s.z += e[j].z; s.w += e[j].w;
  }
#pragma unroll
  for (int j = 0; j < 4; ++j) {
    float4 o = make_float4(e[j].x / s.x, e[j].y / s.y, e[j].z / s.z, e[j].w / s.w);
    *(float4*)&alpha[(size_t)n * 16 + j * 4] = o;
  }
}

// ---------------------------------------------------------------------------
// out[n, h*64+f] = sum_j alpha[n,j,h] * g[nbr_j, h*64+f] + bias; optional ELU.
// ---------------------------------------------------------------------------
template <bool ELU>
__global__ __launch_bounds__(256) void aggregate_kernel(const float* __restrict__ g,
                                                        const int* __restrict__ nbr,
                                                        const float* __restrict__ alpha,
                                                        const float* __restrict__ bias,
                                                        float* __restrict__ y) {
  const int t = threadIdx.x;
  const int lane = t & 63;
  const int n = blockIdx.x * 4 + (t >> 6);
  int4 nb = *(const int4*)&nbr[(size_t)n * 4];
  const int h = lane >> 4;
  const float a0 = alpha[(size_t)n * 16 + 0 + h];
  const float a1 = alpha[(size_t)n * 16 + 4 + h];
  const float a2 = alpha[(size_t)n * 16 + 8 + h];
  const float a3 = alpha[(size_t)n * 16 + 12 + h];
  const int c = lane * 4;
  float4 v0 = *(const float4*)&g[(size_t)nb.x * 256 + c];
  float4 v1 = *(const float4*)&g[(size_t)nb.y * 256 + c];
  float4 v2 = *(const float4*)&g[(size_t)nb.z * 256 + c];
  float4 v3 = *(const float4*)&g[(size_t)nb.w * 256 + c];
  float4 bb = *(const float4*)&bias[c];
  float4 o;
  o.x = a0 * v0.x + a1 * v1.x + a2 * v2.x + a3 * v3.x + bb.x;
  o.y = a0 * v0.y + a1 * v1.y + a2 * v2.y + a3 * v3.y + bb.y;
  o.z = a0 * v0.z + a1 * v1.z + a2 * v2.z + a3 * v3.z + bb.z;
  o.w = a0 * v0.w + a1 * v1.w + a2 * v2.w + a3 * v3.w + bb.w;
  if (ELU) {
    o.x = o.x > 0.f ? o.x : expm1f(o.x);
    o.y = o.y > 0.f ? o.y : expm1f(o.y);
    o.z = o.z > 0.f ? o.z : expm1f(o.z);
    o.w = o.w > 0.f ? o.w : expm1f(o.w);
  }
  *(float4*)&y[(size_t)n * 256 + c] = o;
}

// ---------------------------------------------------------------------------
// Layer 2 projection: g2[n,0..1] = y[n,:] @ W2[:,0..1]; also asrc2/adst2.
// ---------------------------------------------------------------------------
__global__ __launch_bounds__(256) void head2_kernel(const float* __restrict__ y,
                                                    const float* __restrict__ W2,
                                                    const float* __restrict__ as2,
                                                    const float* __restrict__ ad2,
                                                    float* __restrict__ g2,
                                                    float* __restrict__ asrc2,
                                                    float* __restrict__ adst2) {
  const int t = threadIdx.x, lane = t & 63;
  const int n = blockIdx.x * 4 + (t >> 6);
  float4 v  = *(const float4*)&y[(size_t)n * 256 + lane * 4];
  float4 wa = *(const float4*)&W2[lane * 8];      // rows 4l,4l+1 (cols 0,1 each)
  float4 wb = *(const float4*)&W2[lane * 8 + 4];  // rows 4l+2,4l+3
  float p0 = v.x * wa.x + v.y * wa.z + v.z * wb.x + v.w * wb.z;
  float p1 = v.x * wa.y + v.y * wa.w + v.z * wb.y + v.w * wb.w;
#pragma unroll
  for (int off = 1; off < 64; off <<= 1) {
    p0 += __shfl_xor(p0, off);
    p1 += __shfl_xor(p1, off);
  }
  if (lane == 0) {
    g2[(size_t)n * 2]     = p0;
    g2[(size_t)n * 2 + 1] = p1;
    asrc2[n] = p0 * as2[0] + p1 * as2[1];
    adst2[n] = p0 * ad2[0] + p1 * ad2[1];
  }
}

// ---------------------------------------------------------------------------
// Final aggregation (H=1, F=2) + bias -> d_out
// ---------------------------------------------------------------------------
__global__ __launch_bounds__(256) void final_kernel(const int* __restrict__ nbr,
                                                    const float* __restrict__ g2,
                                                    const float* __restrict__ asrc2,
                                                    const float* __restrict__ adst2,
                                                    const float* __restrict__ b2,
                                                    float* __restrict__ out) {
  const int n = blockIdx.x * 256 + threadIdx.x;
  int4 nb = *(const int4*)&nbr[(size_t)n * 4];
  const float ad = adst2[n];
  float e0 = leaky02(asrc2[nb.x] + ad);
  float e1 = leaky02(asrc2[nb.y] + ad);
  float e2 = leaky02(asrc2[nb.z] + ad);
  float e3 = leaky02(asrc2[nb.w] + ad);
  float m = fmaxf(fmaxf(e0, e1), fmaxf(e2, e3));
  float x0 = expf(e0 - m), x1 = expf(e1 - m), x2 = expf(e2 - m), x3 = expf(e3 - m);
  float s = x0 + x1 + x2 + x3;
  float o0 = (x0 * g2[(size_t)nb.x * 2] + x1 * g2[(size_t)nb.y * 2] +
              x2 * g2[(size_t)nb.z * 2] + x3 * g2[(size_t)nb.w * 2]) / s;
  float o1 = (x0 * g2[(size_t)nb.x * 2 + 1] + x1 * g2[(size_t)nb.y * 2 + 1] +
              x2 * g2[(size_t)nb.z * 2 + 1] + x3 * g2[(size_t)nb.w * 2 + 1]) / s;
  out[(size_t)n * 2]     = o0 + b2[0];
  out[(size_t)n * 2 + 1] = o1 + b2[1];
}

extern "C" void kernel_launch(void* const* d_in, const int* in_sizes, int n_in,
                              void* d_out, int out_size, void* d_ws, size_t ws_size,
                              hipStream_t stream) {
  const float* coords = (const float*)d_in[0];
  const float* x   = (const float*)d_in[1];
  const float* W0  = (const float*)d_in[2];
  const float* as0 = (const float*)d_in[3];
  const float* ad0 = (const float*)d_in[4];
  const float* b0  = (const float*)d_in[5];
  const float* W1  = (const float*)d_in[6];
  const float* as1 = (const float*)d_in[7];
  const float* ad1 = (const float*)d_in[8];
  const float* b1  = (const float*)d_in[9];
  const float* W2  = (const float*)d_in[10];
  const float* as2 = (const float*)d_in[11];
  const float* ad2 = (const float*)d_in[12];
  const float* b2  = (const float*)d_in[13];
  float* out = (float*)d_out;

  // workspace carve-up (~273 MiB)
  float* g     = (float*)d_ws;                       // N*256
  float* y     = g + (size_t)Nn * 256;               // N*256
  int*   nbr   = (int*)(y + (size_t)Nn * 256);       // N*4
  float* asrc  = (float*)(nbr + (size_t)Nn * 4);     // N*4
  float* adst  = asrc + (size_t)Nn * 4;              // N*4
  float* alpha = adst + (size_t)Nn * 4;              // N*16
  float* g2    = alpha + (size_t)Nn * 16;            // N*2
  float* s2    = g2 + (size_t)Nn * 2;                // N
  float* d2    = s2 + (size_t)Nn;                    // N
  unsigned short* Wth = (unsigned short*)(d2 + (size_t)Nn);  // 256*256
  unsigned short* Wtl = Wth + 256 * 256;                     // 256*256
  // kNN partials alias g (g is first written later, by the layer-0 GEMM)
  float* pd = g;                       // N*16
  int*   pi = (int*)(g + (size_t)Nn * 16);  // N*16

  knn_partial<<<dim3(Pn / 256, NCH, Bn), 256, 0, stream>>>(coords, pd, pi);
  knn_merge<<<Nn / 256, 256, 0, stream>>>(pd, pi, nbr);

  // Layer 0
  wt_kernel<<<256, 256, 0, stream>>>(W0, Wth, Wtl);
  gemm_bf3<<<dim3(2, Nn / 128), 256, 0, stream>>>(x, Wth, Wtl, g);
  attn_coeff_kernel<<<Nn / 4, 256, 0, stream>>>(g, as0, ad0, asrc, adst);
  alpha_kernel<<<Nn / 256, 256, 0, stream>>>(nbr, asrc, adst, alpha);
  aggregate_kernel<true><<<Nn / 4, 256, 0, stream>>>(g, nbr, alpha, b0, y);

  // Layer 1
  wt_kernel<<<256, 256, 0, stream>>>(W1, Wth, Wtl);
  gemm_bf3<<<dim3(2, Nn / 128), 256, 0, stream>>>(y, Wth, Wtl, g);
  attn_coeff_kernel<<<Nn / 4, 256, 0, stream>>>(g, as1, ad1, asrc, adst);
  alpha_kernel<<<Nn / 256, 256, 0, stream>>>(nbr, asrc, adst, alpha);
  aggregate_kernel<true><<<Nn / 4, 256, 0, stream>>>(g, nbr, alpha, b1, y);

  // Layer 2 (H=1, F=2) + final aggregation
  head2_kernel<<<Nn / 4, 256, 0, stream>>>(y, W2, as2, ad2, g2, s2, d2);
  final_kernel<<<Nn / 256, 256, 0, stream>>>(nbr, g2, s2, d2, b2, out);
}

// Round 6
// 733.092 us; speedup vs baseline: 1.8890x; 1.3650x over previous
//
#include <hip/hip_runtime.h>
#include <math.h>

// Problem constants (B=16, P=8192)
constexpr int Bn = 16, Pn = 8192, Nn = 16 * 8192;
constexpr int GB = 32;            // bins per axis
constexpr int NBIN = GB * GB;     // 1024 bins per batch

typedef __attribute__((ext_vector_type(8))) short short8;
typedef __attribute__((ext_vector_type(4))) float f32x4;

// f32 -> bf16 (round-to-nearest-even), and back
__device__ __forceinline__ unsigned short f2bf(float f) {
  unsigned u = __builtin_bit_cast(unsigned, f);
  unsigned r = (u + 0x7FFFu + ((u >> 16) & 1u)) >> 16;
  return (unsigned short)r;
}
__device__ __forceinline__ float bf2f(unsigned short h) {
  unsigned u = ((unsigned)h) << 16;
  return __builtin_bit_cast(float, u);
}

// ---------------------------------------------------------------------------
// kNN v5: exact spatial-grid kNN. 32x32 bins/batch (~8 pts/bin). Each query
// expands Chebyshev rings until box-margin^2 >= d3 (with 1e-6 abs slack for
// the <=1ulp bin-assignment rounding). Selection by lexicographic (d, idx)
// == lax.top_k stable-tie order; scan-order independent -> deterministic.
// ---------------------------------------------------------------------------
__global__ __launch_bounds__(256) void bin_count(const float* __restrict__ coords,
                                                 int* __restrict__ counts) {
  const int n = blockIdx.x * 256 + threadIdx.x;
  const int b = n >> 13;
  float2 c = ((const float2*)coords)[n];
  int bx = min(GB - 1, (int)(c.x * (float)GB));
  int by = min(GB - 1, (int)(c.y * (float)GB));
  atomicAdd(&counts[b * NBIN + by * GB + bx], 1);
}

__global__ __launch_bounds__(1024) void bin_scan(const int* __restrict__ counts,
                                                 int* __restrict__ starts,
                                                 int* __restrict__ cursor) {
  __shared__ int s[NBIN];
  const int b = blockIdx.x, t = threadIdx.x;
  const int v = counts[b * NBIN + t];
  s[t] = v;
  __syncthreads();
  for (int off = 1; off < NBIN; off <<= 1) {
    int x = (t >= off) ? s[t - off] : 0;
    __syncthreads();
    s[t] += x;
    __syncthreads();
  }
  const int excl = s[t] - v;
  starts[b * NBIN + t] = excl;
  cursor[b * NBIN + t] = excl;
}

__global__ __launch_bounds__(256) void bin_scatter(const float* __restrict__ coords,
                                                   int* __restrict__ cursor,
                                                   float2* __restrict__ pts,
                                                   int* __restrict__ ids) {
  const int n = blockIdx.x * 256 + threadIdx.x;
  const int b = n >> 13, p = n & (Pn - 1);
  float2 c = ((const float2*)coords)[n];
  int bx = min(GB - 1, (int)(c.x * (float)GB));
  int by = min(GB - 1, (int)(c.y * (float)GB));
  int slot = atomicAdd(&cursor[b * NBIN + by * GB + bx], 1);
  pts[(size_t)b * Pn + slot] = c;
  ids[(size_t)b * Pn + slot] = p;
}

__global__ __launch_bounds__(256) void knn_query(const float* __restrict__ coords,
                                                 const int* __restrict__ starts,
                                                 const int* __restrict__ counts,
                                                 const float2* __restrict__ pts,
                                                 const int* __restrict__ ids,
                                                 int* __restrict__ nbr) {
  const int n = blockIdx.x * 256 + threadIdx.x;
  const int b = n >> 13;
  const float2 q = ((const float2*)coords)[n];
  const float qx = q.x, qy = q.y;
  const float w = 1.0f / (float)GB;
  const int bx = min(GB - 1, (int)(qx * (float)GB));
  const int by = min(GB - 1, (int)(qy * (float)GB));
  const float2* bp = pts + (size_t)b * Pn;
  const int* bi = ids + (size_t)b * Pn;
  const int* bs = starts + b * NBIN;
  const int* bc = counts + b * NBIN;

  float d0v = 3.4e38f, d1v = 3.4e38f, d2v = 3.4e38f, d3v = 3.4e38f;
  int i0v = 0x7fffffff, i1v = 0x7fffffff, i2v = 0x7fffffff, i3v = 0x7fffffff;

#define LLT(da, ia, db, ib) ((da) < (db) || ((da) == (db) && (ia) < (ib)))
#define LEX_INSERT(dd, jj)                                              \
  if (LLT(dd, jj, d3v, i3v)) {                                          \
    if (LLT(dd, jj, d2v, i2v)) {                                        \
      d3v = d2v; i3v = i2v;                                             \
      if (LLT(dd, jj, d1v, i1v)) {                                      \
        d2v = d1v; i2v = i1v;                                           \
        if (LLT(dd, jj, d0v, i0v)) { d1v = d0v; i1v = i0v; d0v = dd; i0v = jj; } \
        else { d1v = dd; i1v = jj; }                                    \
      } else { d2v = dd; i2v = jj; }                                    \
    } else { d3v = dd; i3v = jj; }                                      \
  }
#define SCAN_CELL(xx, yy)                                               \
  {                                                                     \
    const int cell = (yy) * GB + (xx);                                  \
    const int s0 = bs[cell], cnt = bc[cell];                            \
    for (int s = s0; s < s0 + cnt; ++s) {                               \
      float2 pp = bp[s];                                                \
      int jj = bi[s];                                                   \
      float dx = qx - pp.x, dy = qy - pp.y;                             \
      float dd = __fadd_rn(__fmul_rn(dx, dx), __fmul_rn(dy, dy));       \
      LEX_INSERT(dd, jj);                                               \
    }                                                                   \
  }

  for (int k = 0; k < GB; ++k) {
    const int xlo = bx - k, xhi = bx + k, ylo = by - k, yhi = by + k;
    const int cxlo = max(0, xlo), cxhi = min(GB - 1, xhi);
    const int cylo = max(0, ylo), cyhi = min(GB - 1, yhi);
    for (int yy = cylo; yy <= cyhi; ++yy) {
      const bool edge = (yy == ylo) || (yy == yhi);
      if (edge || k == 0) {
        for (int xx = cxlo; xx <= cxhi; ++xx) SCAN_CELL(xx, yy);
      } else {
        if (xlo >= 0) SCAN_CELL(xlo, yy);
        if (xhi <= GB - 1) SCAN_CELL(xhi, yy);
      }
    }
    // termination: unscanned points lie outside the (2k+1)^2 box; their
    // distance >= margin (minus tiny slack for bin-assignment rounding).
    float m = 1e30f;
    bool open = false;
    if (xlo > 0)      { m = fminf(m, qx - (float)xlo * w); open = true; }
    if (xhi < GB - 1) { m = fminf(m, (float)(xhi + 1) * w - qx); open = true; }
    if (ylo > 0)      { m = fminf(m, qy - (float)ylo * w); open = true; }
    if (yhi < GB - 1) { m = fminf(m, (float)(yhi + 1) * w - qy); open = true; }
    if (!open) break;  // whole domain scanned
    m -= 1e-6f;
    if (d3v < 3.0e38f && m > 0.f && __fmul_rn(m, m) >= d3v) break;
  }
#undef SCAN_CELL
#undef LEX_INSERT
#undef LLT

  const int base = b * Pn;
  *(int4*)&nbr[(size_t)n * 4] =
      make_int4(base + i0v, base + i1v, base + i2v, base + i3v);
}

// ---------------------------------------------------------------------------
// W [256][256] f32 (row-major [k][n]) -> Wt_h/Wt_l bf16 [n][k] (transposed)
// ---------------------------------------------------------------------------
__global__ __launch_bounds__(256) void wt_kernel(const float* __restrict__ W,
                                                 unsigned short* __restrict__ Wth,
                                                 unsigned short* __restrict__ Wtl) {
  const int k = blockIdx.x, n = threadIdx.x;
  float v = W[k * 256 + n];
  unsigned short h = f2bf(v);
  unsigned short l = f2bf(v - bf2f(h));
  Wth[n * 256 + k] = h;
  Wtl[n * 256 + k] = l;
}

// ---------------------------------------------------------------------------
// bf16x3 MFMA GEMM: C[M,256] = A[M,256] @ W. (unchanged from R4)
// ---------------------------------------------------------------------------
__global__ __launch_bounds__(256, 2) void gemm_bf3(const float* __restrict__ A,
                                                   const unsigned short* __restrict__ Bth,
                                                   const unsigned short* __restrict__ Btl,
                                                   float* __restrict__ C) {
  __shared__ unsigned short Ah[128][40], Al[128][40];
  __shared__ unsigned short Bh[128][40], Bl[128][40];
  const int t = threadIdx.x;
  const int row0 = blockIdx.y * 128;
  const int col0 = blockIdx.x * 128;
  const int wid = t >> 6, lane = t & 63;
  const int wr = (wid >> 1) * 64, wc = (wid & 1) * 64;
  const int lrow = lane & 15, lko = (lane >> 4) * 8;

  f32x4 acc[4][4];
#pragma unroll
  for (int i = 0; i < 4; ++i)
#pragma unroll
    for (int j = 0; j < 4; ++j) acc[i][j] = {0.f, 0.f, 0.f, 0.f};

  for (int kt = 0; kt < 8; ++kt) {
    const int k0 = kt * 32;
    float4 av[4];
#pragma unroll
    for (int i = 0; i < 4; ++i) {
      const int idx = t + i * 256;
      const int row = idx >> 3, kq = idx & 7;
      av[i] = *(const float4*)&A[(size_t)(row0 + row) * 256 + k0 + kq * 4];
    }
    uint4 bh[2], bl[2];
#pragma unroll
    for (int i = 0; i < 2; ++i) {
      const int idx = t + i * 256;
      const int col = idx >> 2, kc = idx & 3;
      bh[i] = *(const uint4*)&Bth[(size_t)(col0 + col) * 256 + k0 + kc * 8];
      bl[i] = *(const uint4*)&Btl[(size_t)(col0 + col) * 256 + k0 + kc * 8];
    }
    __syncthreads();
#pragma unroll
    for (int i = 0; i < 4; ++i) {
      const int idx = t + i * 256;
      const int row = idx >> 3, kq = idx & 7;
      const float vv[4] = {av[i].x, av[i].y, av[i].z, av[i].w};
      unsigned short hh[4], ll[4];
#pragma unroll
      for (int e = 0; e < 4; ++e) {
        hh[e] = f2bf(vv[e]);
        ll[e] = f2bf(vv[e] - bf2f(hh[e]));
      }
      *(ushort4*)&Ah[row][kq * 4] = make_ushort4(hh[0], hh[1], hh[2], hh[3]);
      *(ushort4*)&Al[row][kq * 4] = make_ushort4(ll[0], ll[1], ll[2], ll[3]);
    }
#pragma unroll
    for (int i = 0; i < 2; ++i) {
      const int idx = t + i * 256;
      const int col = idx >> 2, kc = idx & 3;
      *(uint4*)&Bh[col][kc * 8] = bh[i];
      *(uint4*)&Bl[col][kc * 8] = bl[i];
    }
    __syncthreads();
    short8 afh[4], afl[4], bfh[4], bfl[4];
#pragma unroll
    for (int f = 0; f < 4; ++f) {
      afh[f] = *(const short8*)&Ah[wr + f * 16 + lrow][lko];
      afl[f] = *(const short8*)&Al[wr + f * 16 + lrow][lko];
      bfh[f] = *(const short8*)&Bh[wc + f * 16 + lrow][lko];
      bfl[f] = *(const short8*)&Bl[wc + f * 16 + lrow][lko];
    }
#pragma unroll
    for (int fr = 0; fr < 4; ++fr)
#pragma unroll
      for (int fc = 0; fc < 4; ++fc) {
        acc[fr][fc] = __builtin_amdgcn_mfma_f32_16x16x32_bf16(afh[fr], bfh[fc], acc[fr][fc], 0, 0, 0);
        acc[fr][fc] = __builtin_amdgcn_mfma_f32_16x16x32_bf16(afh[fr], bfl[fc], acc[fr][fc], 0, 0, 0);
        acc[fr][fc] = __builtin_amdgcn_mfma_f32_16x16x32_bf16(afl[fr], bfh[fc], acc[fr][fc], 0, 0, 0);
      }
  }
#pragma unroll
  for (int fr = 0; fr < 4; ++fr)
#pragma unroll
    for (int fc = 0; fc < 4; ++fc) {
      const int col = col0 + wc + fc * 16 + (lane & 15);
#pragma unroll
      for (int j = 0; j < 4; ++j) {
        const int row = row0 + wr + fr * 16 + (lane >> 4) * 4 + j;
        C[(size_t)row * 256 + col] = acc[fr][fc][j];
      }
    }
}

// ---------------------------------------------------------------------------
// asrc[n,h] = sum_f g[n, h*64+f] * att_src[h,f]; same for adst. 16 lanes/node.
// ---------------------------------------------------------------------------
__global__ __launch_bounds__(256) void attn_coeff_kernel(const float* __restrict__ g,
                                                         const float* __restrict__ att_src,
                                                         const float* __restrict__ att_dst,
                                                         float* __restrict__ asrc,
                                                         float* __restrict__ adst) {
  const int t = threadIdx.x;
  const int lane = t & 63;
  const int n = blockIdx.x * 4 + (t >> 6);
  float4 v  = *(const float4*)&g[(size_t)n * 256 + lane * 4];
  float4 as = *(const float4*)&att_src[lane * 4];
  float4 ad = *(const float4*)&att_dst[lane * 4];
  float ps = v.x * as.x + v.y * as.y + v.z * as.z + v.w * as.w;
  float pd = v.x * ad.x + v.y * ad.y + v.z * ad.z + v.w * ad.w;
#pragma unroll
  for (int off = 1; off < 16; off <<= 1) {
    ps += __shfl_xor(ps, off);
    pd += __shfl_xor(pd, off);
  }
  if ((lane & 15) == 0) {
    asrc[(size_t)n * 4 + (lane >> 4)] = ps;
    adst[(size_t)n * 4 + (lane >> 4)] = pd;
  }
}

__device__ __forceinline__ float leaky02(float x) { return x >= 0.f ? x : 0.2f * x; }

// ---------------------------------------------------------------------------
// Fused alpha + aggregate (+ELU) -> y.  alpha computed inline per 16-lane
// head group (same formula/order as the old alpha_kernel).
// ---------------------------------------------------------------------------
__global__ __launch_bounds__(256) void aggregate_fused(const float* __restrict__ g,
                                                       const int* __restrict__ nbr,
                                                       const float* __restrict__ asrc,
                                                       const float* __restrict__ adst,
                                                       const float* __restrict__ bias,
                                                       float* __restrict__ y) {
  const int t = threadIdx.x;
  const int lane = t & 63;
  const int n = blockIdx.x * 4 + (t >> 6);
  int4 nb = *(const int4*)&nbr[(size_t)n * 4];
  const int h = lane >> 4;
  // inline alpha for head h
  const float adh = adst[(size_t)n * 4 + h];
  float e0 = leaky02(asrc[(size_t)nb.x * 4 + h] + adh);
  float e1 = leaky02(asrc[(size_t)nb.y * 4 + h] + adh);
  float e2 = leaky02(asrc[(size_t)nb.z * 4 + h] + adh);
  float e3 = leaky02(asrc[(size_t)nb.w * 4 + h] + adh);
  float m = fmaxf(fmaxf(fmaxf(e0, e1), e2), e3);
  float x0 = expf(e0 - m), x1 = expf(e1 - m), x2 = expf(e2 - m), x3 = expf(e3 - m);
  float s = ((x0 + x1) + x2) + x3;
  const float a0 = x0 / s, a1 = x1 / s, a2 = x2 / s, a3 = x3 / s;

  const int c = lane * 4;
  float4 v0 = *(const float4*)&g[(size_t)nb.x * 256 + c];
  float4 v1 = *(const float4*)&g[(size_t)nb.y * 256 + c];
  float4 v2 = *(const float4*)&g[(size_t)nb.z * 256 + c];
  float4 v3 = *(const float4*)&g[(size_t)nb.w * 256 + c];
  float4 bb = *(const float4*)&bias[c];
  float4 o;
  o.x = a0 * v0.x + a1 * v1.x + a2 * v2.x + a3 * v3.x + bb.x;
  o.y = a0 * v0.y + a1 * v1.y + a2 * v2.y + a3 * v3.y + bb.y;
  o.z = a0 * v0.z + a1 * v1.z + a2 * v2.z + a3 * v3.z + bb.z;
  o.w = a0 * v0.w + a1 * v1.w + a2 * v2.w + a3 * v3.w + bb.w;
  o.x = o.x > 0.f ? o.x : expm1f(o.x);
  o.y = o.y > 0.f ? o.y : expm1f(o.y);
  o.z = o.z > 0.f ? o.z : expm1f(o.z);
  o.w = o.w > 0.f ? o.w : expm1f(o.w);
  *(float4*)&y[(size_t)n * 256 + c] = o;
}

// ---------------------------------------------------------------------------
// Layer-1 aggregate fused with ELU + head2 projection: skips writing y;
// produces g2[n][2], asrc2[n], adst2[n] directly (full-wave reduction).
// ---------------------------------------------------------------------------
__global__ __launch_bounds__(256) void aggregate_h2(const float* __restrict__ g,
                                                    const int* __restrict__ nbr,
                                                    const float* __restrict__ asrc,
                                                    const float* __restrict__ adst,
                                                    const float* __restrict__ bias,
                                                    const float* __restrict__ W2,
                                                    const float* __restrict__ as2,
                                                    const float* __restrict__ ad2,
                                                    float* __restrict__ g2,
                                                    float* __restrict__ asrc2,
                                                    float* __restrict__ adst2) {
  const int t = threadIdx.x;
  const int lane = t & 63;
  const int n = blockIdx.x * 4 + (t >> 6);
  int4 nb = *(const int4*)&nbr[(size_t)n * 4];
  const int h = lane >> 4;
  const float adh = adst[(size_t)n * 4 + h];
  float e0 = leaky02(asrc[(size_t)nb.x * 4 + h] + adh);
  float e1 = leaky02(asrc[(size_t)nb.y * 4 + h] + adh);
  float e2 = leaky02(asrc[(size_t)nb.z * 4 + h] + adh);
  float e3 = leaky02(asrc[(size_t)nb.w * 4 + h] + adh);
  float m = fmaxf(fmaxf(fmaxf(e0, e1), e2), e3);
  float x0 = expf(e0 - m), x1 = expf(e1 - m), x2 = expf(e2 - m), x3 = expf(e3 - m);
  float s = ((x0 + x1) + x2) + x3;
  const float a0 = x0 / s, a1 = x1 / s, a2 = x2 / s, a3 = x3 / s;

  const int c = lane * 4;
  float4 v0 = *(const float4*)&g[(size_t)nb.x * 256 + c];
  float4 v1 = *(const float4*)&g[(size_t)nb.y * 256 + c];
  float4 v2 = *(const float4*)&g[(size_t)nb.z * 256 + c];
  float4 v3 = *(const float4*)&g[(size_t)nb.w * 256 + c];
  float4 bb = *(const float4*)&bias[c];
  float4 o;
  o.x = a0 * v0.x + a1 * v1.x + a2 * v2.x + a3 * v3.x + bb.x;
  o.y = a0 * v0.y + a1 * v1.y + a2 * v2.y + a3 * v3.y + bb.y;
  o.z = a0 * v0.z + a1 * v1.z + a2 * v2.z + a3 * v3.z + bb.z;
  o.w = a0 * v0.w + a1 * v1.w + a2 * v2.w + a3 * v3.w + bb.w;
  o.x = o.x > 0.f ? o.x : expm1f(o.x);
  o.y = o.y > 0.f ? o.y : expm1f(o.y);
  o.z = o.z > 0.f ? o.z : expm1f(o.z);
  o.w = o.w > 0.f ? o.w : expm1f(o.w);

  // head2: p = o . W2[c..c+3][0..1], full-wave reduce (same order as before)
  const float w00 = W2[(c + 0) * 2 + 0], w01 = W2[(c + 0) * 2 + 1];
  const float w10 = W2[(c + 1) * 2 + 0], w11 = W2[(c + 1) * 2 + 1];
  const float w20 = W2[(c + 2) * 2 + 0], w21 = W2[(c + 2) * 2 + 1];
  const float w30 = W2[(c + 3) * 2 + 0], w31 = W2[(c + 3) * 2 + 1];
  float p0 = o.x * w00 + o.y * w10 + o.z * w20 + o.w * w30;
  float p1 = o.x * w01 + o.y * w11 + o.z * w21 + o.w * w31;
#pragma unroll
  for (int off = 1; off < 64; off <<= 1) {
    p0 += __shfl_xor(p0, off);
    p1 += __shfl_xor(p1, off);
  }
  if (lane == 0) {
    g2[(size_t)n * 2]     = p0;
    g2[(size_t)n * 2 + 1] = p1;
    asrc2[n] = p0 * as2[0] + p1 * as2[1];
    adst2[n] = p0 * ad2[0] + p1 * ad2[1];
  }
}

// ---------------------------------------------------------------------------
// Final aggregation (H=1, F=2) + bias -> d_out
// ---------------------------------------------------------------------------
__global__ __launch_bounds__(256) void final_kernel(const int* __restrict__ nbr,
                                                    const float* __restrict__ g2,
                                                    const float* __restrict__ asrc2,
                                                    const float* __restrict__ adst2,
                                                    const float* __restrict__ b2,
                                                    float* __restrict__ out) {
  const int n = blockIdx.x * 256 + threadIdx.x;
  int4 nb = *(const int4*)&nbr[(size_t)n * 4];
  const float ad = adst2[n];
  float e0 = leaky02(asrc2[nb.x] + ad);
  float e1 = leaky02(asrc2[nb.y] + ad);
  float e2 = leaky02(asrc2[nb.z] + ad);
  float e3 = leaky02(asrc2[nb.w] + ad);
  float m = fmaxf(fmaxf(e0, e1), fmaxf(e2, e3));
  float x0 = expf(e0 - m), x1 = expf(e1 - m), x2 = expf(e2 - m), x3 = expf(e3 - m);
  float s = x0 + x1 + x2 + x3;
  float o0 = (x0 * g2[(size_t)nb.x * 2] + x1 * g2[(size_t)nb.y * 2] +
              x2 * g2[(size_t)nb.z * 2] + x3 * g2[(size_t)nb.w * 2]) / s;
  float o1 = (x0 * g2[(size_t)nb.x * 2 + 1] + x1 * g2[(size_t)nb.y * 2 + 1] +
              x2 * g2[(size_t)nb.z * 2 + 1] + x3 * g2[(size_t)nb.w * 2 + 1]) / s;
  out[(size_t)n * 2]     = o0 + b2[0];
  out[(size_t)n * 2 + 1] = o1 + b2[1];
}

extern "C" void kernel_launch(void* const* d_in, const int* in_sizes, int n_in,
                              void* d_out, int out_size, void* d_ws, size_t ws_size,
                              hipStream_t stream) {
  const float* coords = (const float*)d_in[0];
  const float* x   = (const float*)d_in[1];
  const float* W0  = (const float*)d_in[2];
  const float* as0 = (const float*)d_in[3];
  const float* ad0 = (const float*)d_in[4];
  const float* b0  = (const float*)d_in[5];
  const float* W1  = (const float*)d_in[6];
  const float* as1 = (const float*)d_in[7];
  const float* ad1 = (const float*)d_in[8];
  const float* b1  = (const float*)d_in[9];
  const float* W2  = (const float*)d_in[10];
  const float* as2 = (const float*)d_in[11];
  const float* ad2 = (const float*)d_in[12];
  const float* b2  = (const float*)d_in[13];
  float* out = (float*)d_out;

  // workspace carve-up
  float* g     = (float*)d_ws;                       // N*256
  float* y     = g + (size_t)Nn * 256;               // N*256
  int*   nbr   = (int*)(y + (size_t)Nn * 256);       // N*4
  float* asrc  = (float*)(nbr + (size_t)Nn * 4);     // N*4
  float* adst  = asrc + (size_t)Nn * 4;              // N*4
  float* g2    = adst + (size_t)Nn * 4;              // N*2
  float* s2    = g2 + (size_t)Nn * 2;                // N
  float* d2    = s2 + (size_t)Nn;                    // N
  unsigned short* Wth = (unsigned short*)(d2 + (size_t)Nn);  // 256*256
  unsigned short* Wtl = Wth + 256 * 256;                     // 256*256
  float2* pts  = (float2*)(Wtl + 256 * 256);         // Bn*Pn float2
  int* ids     = (int*)(pts + (size_t)Bn * Pn);      // Bn*Pn
  int* counts  = ids + (size_t)Bn * Pn;              // Bn*NBIN
  int* starts  = counts + Bn * NBIN;                 // Bn*NBIN
  int* cursor  = starts + Bn * NBIN;                 // Bn*NBIN

  // kNN: bin -> scan -> scatter -> ring query
  hipMemsetAsync(counts, 0, Bn * NBIN * sizeof(int), stream);
  bin_count<<<Nn / 256, 256, 0, stream>>>(coords, counts);
  bin_scan<<<Bn, NBIN, 0, stream>>>(counts, starts, cursor);
  bin_scatter<<<Nn / 256, 256, 0, stream>>>(coords, cursor, pts, ids);
  knn_query<<<Nn / 256, 256, 0, stream>>>(coords, starts, counts, pts, ids, nbr);

  // Layer 0
  wt_kernel<<<256, 256, 0, stream>>>(W0, Wth, Wtl);
  gemm_bf3<<<dim3(2, Nn / 128), 256, 0, stream>>>(x, Wth, Wtl, g);
  attn_coeff_kernel<<<Nn / 4, 256, 0, stream>>>(g, as0, ad0, asrc, adst);
  aggregate_fused<<<Nn / 4, 256, 0, stream>>>(g, nbr, asrc, adst, b0, y);

  // Layer 1
  wt_kernel<<<256, 256, 0, stream>>>(W1, Wth, Wtl);
  gemm_bf3<<<dim3(2, Nn / 128), 256, 0, stream>>>(y, Wth, Wtl, g);
  attn_coeff_kernel<<<Nn / 4, 256, 0, stream>>>(g, as1, ad1, asrc, adst);
  aggregate_h2<<<Nn / 4, 256, 0, stream>>>(g, nbr, asrc, adst, b1, W2, as2, ad2,
                                           g2, s2, d2);

  // Final aggregation (H=1, F=2)
  final_kernel<<<Nn / 256, 256, 0, stream>>>(nbr, g2, s2, d2, b2, out);
}

// Round 7
// 706.650 us; speedup vs baseline: 1.9597x; 1.0374x over previous
//
#include <hip/hip_runtime.h>
#include <math.h>

// Problem constants (B=16, P=8192)
constexpr int Bn = 16, Pn = 8192, Nn = 16 * 8192;
constexpr int GB = 32;            // bins per axis
constexpr int NBIN = GB * GB;     // 1024 bins per batch

typedef __attribute__((ext_vector_type(8))) short short8;
typedef __attribute__((ext_vector_type(4))) float f32x4;

// f32 -> bf16 (round-to-nearest-even), and back
__device__ __forceinline__ unsigned short f2bf(float f) {
  unsigned u = __builtin_bit_cast(unsigned, f);
  unsigned r = (u + 0x7FFFu + ((u >> 16) & 1u)) >> 16;
  return (unsigned short)r;
}
__device__ __forceinline__ float bf2f(unsigned short h) {
  unsigned u = ((unsigned)h) << 16;
  return __builtin_bit_cast(float, u);
}

// ---------------------------------------------------------------------------
// kNN: exact spatial-grid kNN (unchanged from R5 — no longer a top cost).
// ---------------------------------------------------------------------------
__global__ __launch_bounds__(256) void bin_count(const float* __restrict__ coords,
                                                 int* __restrict__ counts) {
  const int n = blockIdx.x * 256 + threadIdx.x;
  const int b = n >> 13;
  float2 c = ((const float2*)coords)[n];
  int bx = min(GB - 1, (int)(c.x * (float)GB));
  int by = min(GB - 1, (int)(c.y * (float)GB));
  atomicAdd(&counts[b * NBIN + by * GB + bx], 1);
}

__global__ __launch_bounds__(1024) void bin_scan(const int* __restrict__ counts,
                                                 int* __restrict__ starts,
                                                 int* __restrict__ cursor) {
  __shared__ int s[NBIN];
  const int b = blockIdx.x, t = threadIdx.x;
  const int v = counts[b * NBIN + t];
  s[t] = v;
  __syncthreads();
  for (int off = 1; off < NBIN; off <<= 1) {
    int x = (t >= off) ? s[t - off] : 0;
    __syncthreads();
    s[t] += x;
    __syncthreads();
  }
  const int excl = s[t] - v;
  starts[b * NBIN + t] = excl;
  cursor[b * NBIN + t] = excl;
}

__global__ __launch_bounds__(256) void bin_scatter(const float* __restrict__ coords,
                                                   int* __restrict__ cursor,
                                                   float2* __restrict__ pts,
                                                   int* __restrict__ ids) {
  const int n = blockIdx.x * 256 + threadIdx.x;
  const int b = n >> 13, p = n & (Pn - 1);
  float2 c = ((const float2*)coords)[n];
  int bx = min(GB - 1, (int)(c.x * (float)GB));
  int by = min(GB - 1, (int)(c.y * (float)GB));
  int slot = atomicAdd(&cursor[b * NBIN + by * GB + bx], 1);
  pts[(size_t)b * Pn + slot] = c;
  ids[(size_t)b * Pn + slot] = p;
}

__global__ __launch_bounds__(256) void knn_query(const float* __restrict__ coords,
                                                 const int* __restrict__ starts,
                                                 const int* __restrict__ counts,
                                                 const float2* __restrict__ pts,
                                                 const int* __restrict__ ids,
                                                 int* __restrict__ nbr) {
  const int n = blockIdx.x * 256 + threadIdx.x;
  const int b = n >> 13;
  const float2 q = ((const float2*)coords)[n];
  const float qx = q.x, qy = q.y;
  const float w = 1.0f / (float)GB;
  const int bx = min(GB - 1, (int)(qx * (float)GB));
  const int by = min(GB - 1, (int)(qy * (float)GB));
  const float2* bp = pts + (size_t)b * Pn;
  const int* bi = ids + (size_t)b * Pn;
  const int* bs = starts + b * NBIN;
  const int* bc = counts + b * NBIN;

  float d0v = 3.4e38f, d1v = 3.4e38f, d2v = 3.4e38f, d3v = 3.4e38f;
  int i0v = 0x7fffffff, i1v = 0x7fffffff, i2v = 0x7fffffff, i3v = 0x7fffffff;

#define LLT(da, ia, db, ib) ((da) < (db) || ((da) == (db) && (ia) < (ib)))
#define LEX_INSERT(dd, jj)                                              \
  if (LLT(dd, jj, d3v, i3v)) {                                          \
    if (LLT(dd, jj, d2v, i2v)) {                                        \
      d3v = d2v; i3v = i2v;                                             \
      if (LLT(dd, jj, d1v, i1v)) {                                      \
        d2v = d1v; i2v = i1v;                                           \
        if (LLT(dd, jj, d0v, i0v)) { d1v = d0v; i1v = i0v; d0v = dd; i0v = jj; } \
        else { d1v = dd; i1v = jj; }                                    \
      } else { d2v = dd; i2v = jj; }                                    \
    } else { d3v = dd; i3v = jj; }                                      \
  }
#define SCAN_CELL(xx, yy)                                               \
  {                                                                     \
    const int cell = (yy) * GB + (xx);                                  \
    const int s0 = bs[cell], cnt = bc[cell];                            \
    for (int s = s0; s < s0 + cnt; ++s) {                               \
      float2 pp = bp[s];                                                \
      int jj = bi[s];                                                   \
      float dx = qx - pp.x, dy = qy - pp.y;                             \
      float dd = __fadd_rn(__fmul_rn(dx, dx), __fmul_rn(dy, dy));       \
      LEX_INSERT(dd, jj);                                               \
    }                                                                   \
  }

  for (int k = 0; k < GB; ++k) {
    const int xlo = bx - k, xhi = bx + k, ylo = by - k, yhi = by + k;
    const int cxlo = max(0, xlo), cxhi = min(GB - 1, xhi);
    const int cylo = max(0, ylo), cyhi = min(GB - 1, yhi);
    for (int yy = cylo; yy <= cyhi; ++yy) {
      const bool edge = (yy == ylo) || (yy == yhi);
      if (edge || k == 0) {
        for (int xx = cxlo; xx <= cxhi; ++xx) SCAN_CELL(xx, yy);
      } else {
        if (xlo >= 0) SCAN_CELL(xlo, yy);
        if (xhi <= GB - 1) SCAN_CELL(xhi, yy);
      }
    }
    float m = 1e30f;
    bool open = false;
    if (xlo > 0)      { m = fminf(m, qx - (float)xlo * w); open = true; }
    if (xhi < GB - 1) { m = fminf(m, (float)(xhi + 1) * w - qx); open = true; }
    if (ylo > 0)      { m = fminf(m, qy - (float)ylo * w); open = true; }
    if (yhi < GB - 1) { m = fminf(m, (float)(yhi + 1) * w - qy); open = true; }
    if (!open) break;
    m -= 1e-6f;
    if (d3v < 3.0e38f && m > 0.f && __fmul_rn(m, m) >= d3v) break;
  }
#undef SCAN_CELL
#undef LEX_INSERT
#undef LLT

  const int base = b * Pn;
  *(int4*)&nbr[(size_t)n * 4] =
      make_int4(base + i0v, base + i1v, base + i2v, base + i3v);
}

// ---------------------------------------------------------------------------
// W [256][256] f32 (row-major [k][n]) -> Wt_h/Wt_l bf16 [n][k] (transposed)
// ---------------------------------------------------------------------------
__global__ __launch_bounds__(256) void wt_kernel(const float* __restrict__ W,
                                                 unsigned short* __restrict__ Wth,
                                                 unsigned short* __restrict__ Wtl) {
  const int k = blockIdx.x, n = threadIdx.x;
  float v = W[k * 256 + n];
  unsigned short h = f2bf(v);
  unsigned short l = f2bf(v - bf2f(h));
  Wth[n * 256 + k] = h;
  Wtl[n * 256 + k] = l;
}

// ---------------------------------------------------------------------------
// bf16x3 MFMA GEMM v2 + fused attention projections.
// C[M,256] = A[M,256] @ W;  asrc[n,h] = sum_f C[n,h*64+f]*att_src[h,f] (same
// for adst) computed in the epilogue (each wave's 64 cols == one head).
// Pipeline: reg-staged loads for kt+1 issued after the stage barrier so HBM
// latency hides under kt's ds_reads+MFMA. LDS stride 36 (72B): frag-read
// rows 0..15 hit 16 distinct banks (2-way max, free).
// ---------------------------------------------------------------------------
__global__ __launch_bounds__(256, 3) void gemm_bf3(const float* __restrict__ A,
                                                   const unsigned short* __restrict__ Bth,
                                                   const unsigned short* __restrict__ Btl,
                                                   const float* __restrict__ att_src,
                                                   const float* __restrict__ att_dst,
                                                   float* __restrict__ C,
                                                   float* __restrict__ asrc,
                                                   float* __restrict__ adst) {
  __shared__ unsigned short Ah[128][36], Al[128][36];
  __shared__ unsigned short Bh[128][36], Bl[128][36];
  const int t = threadIdx.x;
  const int row0 = blockIdx.y * 128;
  const int col0 = blockIdx.x * 128;
  const int wid = t >> 6, lane = t & 63;
  const int wr = (wid >> 1) * 64, wc = (wid & 1) * 64;
  const int lrow = lane & 15, lko = (lane >> 4) * 8;

  f32x4 acc[4][4];
#pragma unroll
  for (int i = 0; i < 4; ++i)
#pragma unroll
    for (int j = 0; j < 4; ++j) acc[i][j] = {0.f, 0.f, 0.f, 0.f};

  float4 av[4];
  uint4 bhv[2], blv[2];

#define GLOAD(ktv)                                                          \
  {                                                                         \
    const int k0 = (ktv) * 32;                                              \
    _Pragma("unroll")                                                       \
    for (int i = 0; i < 4; ++i) {                                           \
      const int idx = t + i * 256;                                          \
      const int row = idx >> 3, kq = idx & 7;                               \
      av[i] = *(const float4*)&A[(size_t)(row0 + row) * 256 + k0 + kq * 4]; \
    }                                                                       \
    _Pragma("unroll")                                                       \
    for (int i = 0; i < 2; ++i) {                                           \
      const int idx = t + i * 256;                                          \
      const int col = idx >> 2, kc = idx & 3;                               \
      bhv[i] = *(const uint4*)&Bth[(size_t)(col0 + col) * 256 + k0 + kc * 8]; \
      blv[i] = *(const uint4*)&Btl[(size_t)(col0 + col) * 256 + k0 + kc * 8]; \
    }                                                                       \
  }

  GLOAD(0);
  for (int kt = 0; kt < 8; ++kt) {
    __syncthreads();  // previous iter's frag reads done
#pragma unroll
    for (int i = 0; i < 4; ++i) {
      const int idx = t + i * 256;
      const int row = idx >> 3, kq = idx & 7;
      const float vv[4] = {av[i].x, av[i].y, av[i].z, av[i].w};
      unsigned short hh[4], ll[4];
#pragma unroll
      for (int e = 0; e < 4; ++e) {
        hh[e] = f2bf(vv[e]);
        ll[e] = f2bf(vv[e] - bf2f(hh[e]));
      }
      *(ushort4*)&Ah[row][kq * 4] = make_ushort4(hh[0], hh[1], hh[2], hh[3]);
      *(ushort4*)&Al[row][kq * 4] = make_ushort4(ll[0], ll[1], ll[2], ll[3]);
    }
#pragma unroll
    for (int i = 0; i < 2; ++i) {
      const int idx = t + i * 256;
      const int col = idx >> 2, kc = idx & 3;
      *(uint4*)&Bh[col][kc * 8] = bhv[i];
      *(uint4*)&Bl[col][kc * 8] = blv[i];
    }
    __syncthreads();
    if (kt < 7) GLOAD(kt + 1);  // issue next tile; retires under MFMA below
    short8 afh[4], afl[4], bfh[4], bfl[4];
#pragma unroll
    for (int f = 0; f < 4; ++f) {
      afh[f] = *(const short8*)&Ah[wr + f * 16 + lrow][lko];
      afl[f] = *(const short8*)&Al[wr + f * 16 + lrow][lko];
      bfh[f] = *(const short8*)&Bh[wc + f * 16 + lrow][lko];
      bfl[f] = *(const short8*)&Bl[wc + f * 16 + lrow][lko];
    }
#pragma unroll
    for (int fr = 0; fr < 4; ++fr)
#pragma unroll
      for (int fc = 0; fc < 4; ++fc) {
        acc[fr][fc] = __builtin_amdgcn_mfma_f32_16x16x32_bf16(afh[fr], bfh[fc], acc[fr][fc], 0, 0, 0);
        acc[fr][fc] = __builtin_amdgcn_mfma_f32_16x16x32_bf16(afh[fr], bfl[fc], acc[fr][fc], 0, 0, 0);
        acc[fr][fc] = __builtin_amdgcn_mfma_f32_16x16x32_bf16(afl[fr], bfh[fc], acc[fr][fc], 0, 0, 0);
      }
  }
#undef GLOAD

  // --- C stores: C/D layout col=lane&15, row=(lane>>4)*4+j (m89) ---
#pragma unroll
  for (int fr = 0; fr < 4; ++fr)
#pragma unroll
    for (int fc = 0; fc < 4; ++fc) {
      const int col = col0 + wc + fc * 16 + lrow;
#pragma unroll
      for (int j = 0; j < 4; ++j) {
        const int row = row0 + wr + fr * 16 + (lane >> 4) * 4 + j;
        C[(size_t)row * 256 + col] = acc[fr][fc][j];
      }
    }

  // --- fused attention projections: this wave's 64 cols == head h ---
  const int h = (col0 >> 6) + (wid & 1);
  float asv[4], adv[4];
#pragma unroll
  for (int fc = 0; fc < 4; ++fc) {
    asv[fc] = att_src[h * 64 + fc * 16 + lrow];
    adv[fc] = att_dst[h * 64 + fc * 16 + lrow];
  }
#pragma unroll
  for (int fr = 0; fr < 4; ++fr)
#pragma unroll
    for (int j = 0; j < 4; ++j) {
      float ps = 0.f, pd = 0.f;
#pragma unroll
      for (int fc = 0; fc < 4; ++fc) {
        ps += acc[fr][fc][j] * asv[fc];
        pd += acc[fr][fc][j] * adv[fc];
      }
#pragma unroll
      for (int off = 1; off < 16; off <<= 1) {
        ps += __shfl_xor(ps, off);
        pd += __shfl_xor(pd, off);
      }
      if (lrow == 0) {
        const int row = row0 + wr + fr * 16 + (lane >> 4) * 4 + j;
        asrc[(size_t)row * 4 + h] = ps;
        adst[(size_t)row * 4 + h] = pd;
      }
    }
}

__device__ __forceinline__ float leaky02(float x) { return x >= 0.f ? x : 0.2f * x; }

// ---------------------------------------------------------------------------
// Fused alpha + aggregate (+ELU) -> y.
// ---------------------------------------------------------------------------
__global__ __launch_bounds__(256) void aggregate_fused(const float* __restrict__ g,
                                                       const int* __restrict__ nbr,
                                                       const float* __restrict__ asrc,
                                                       const float* __restrict__ adst,
                                                       const float* __restrict__ bias,
                                                       float* __restrict__ y) {
  const int t = threadIdx.x;
  const int lane = t & 63;
  const int n = blockIdx.x * 4 + (t >> 6);
  int4 nb = *(const int4*)&nbr[(size_t)n * 4];
  const int h = lane >> 4;
  const float adh = adst[(size_t)n * 4 + h];
  float e0 = leaky02(asrc[(size_t)nb.x * 4 + h] + adh);
  float e1 = leaky02(asrc[(size_t)nb.y * 4 + h] + adh);
  float e2 = leaky02(asrc[(size_t)nb.z * 4 + h] + adh);
  float e3 = leaky02(asrc[(size_t)nb.w * 4 + h] + adh);
  float m = fmaxf(fmaxf(fmaxf(e0, e1), e2), e3);
  float x0 = expf(e0 - m), x1 = expf(e1 - m), x2 = expf(e2 - m), x3 = expf(e3 - m);
  float s = ((x0 + x1) + x2) + x3;
  const float a0 = x0 / s, a1 = x1 / s, a2 = x2 / s, a3 = x3 / s;

  const int c = lane * 4;
  float4 v0 = *(const float4*)&g[(size_t)nb.x * 256 + c];
  float4 v1 = *(const float4*)&g[(size_t)nb.y * 256 + c];
  float4 v2 = *(const float4*)&g[(size_t)nb.z * 256 + c];
  float4 v3 = *(const float4*)&g[(size_t)nb.w * 256 + c];
  float4 bb = *(const float4*)&bias[c];
  float4 o;
  o.x = a0 * v0.x + a1 * v1.x + a2 * v2.x + a3 * v3.x + bb.x;
  o.y = a0 * v0.y + a1 * v1.y + a2 * v2.y + a3 * v3.y + bb.y;
  o.z = a0 * v0.z + a1 * v1.z + a2 * v2.z + a3 * v3.z + bb.z;
  o.w = a0 * v0.w + a1 * v1.w + a2 * v2.w + a3 * v3.w + bb.w;
  o.x = o.x > 0.f ? o.x : expm1f(o.x);
  o.y = o.y > 0.f ? o.y : expm1f(o.y);
  o.z = o.z > 0.f ? o.z : expm1f(o.z);
  o.w = o.w > 0.f ? o.w : expm1f(o.w);
  *(float4*)&y[(size_t)n * 256 + c] = o;
}

// ---------------------------------------------------------------------------
// Layer-1 aggregate fused with ELU + head2 projection.
// ---------------------------------------------------------------------------
__global__ __launch_bounds__(256) void aggregate_h2(const float* __restrict__ g,
                                                    const int* __restrict__ nbr,
                                                    const float* __restrict__ asrc,
                                                    const float* __restrict__ adst,
                                                    const float* __restrict__ bias,
                                                    const float* __restrict__ W2,
                                                    const float* __restrict__ as2,
                                                    const float* __restrict__ ad2,
                                                    float* __restrict__ g2,
                                                    float* __restrict__ asrc2,
                                                    float* __restrict__ adst2) {
  const int t = threadIdx.x;
  const int lane = t & 63;
  const int n = blockIdx.x * 4 + (t >> 6);
  int4 nb = *(const int4*)&nbr[(size_t)n * 4];
  const int h = lane >> 4;
  const float adh = adst[(size_t)n * 4 + h];
  float e0 = leaky02(asrc[(size_t)nb.x * 4 + h] + adh);
  float e1 = leaky02(asrc[(size_t)nb.y * 4 + h] + adh);
  float e2 = leaky02(asrc[(size_t)nb.z * 4 + h] + adh);
  float e3 = leaky02(asrc[(size_t)nb.w * 4 + h] + adh);
  float m = fmaxf(fmaxf(fmaxf(e0, e1), e2), e3);
  float x0 = expf(e0 - m), x1 = expf(e1 - m), x2 = expf(e2 - m), x3 = expf(e3 - m);
  float s = ((x0 + x1) + x2) + x3;
  const float a0 = x0 / s, a1 = x1 / s, a2 = x2 / s, a3 = x3 / s;

  const int c = lane * 4;
  float4 v0 = *(const float4*)&g[(size_t)nb.x * 256 + c];
  float4 v1 = *(const float4*)&g[(size_t)nb.y * 256 + c];
  float4 v2 = *(const float4*)&g[(size_t)nb.z * 256 + c];
  float4 v3 = *(const float4*)&g[(size_t)nb.w * 256 + c];
  float4 bb = *(const float4*)&bias[c];
  float4 o;
  o.x = a0 * v0.x + a1 * v1.x + a2 * v2.x + a3 * v3.x + bb.x;
  o.y = a0 * v0.y + a1 * v1.y + a2 * v2.y + a3 * v3.y + bb.y;
  o.z = a0 * v0.z + a1 * v1.z + a2 * v2.z + a3 * v3.z + bb.z;
  o.w = a0 * v0.w + a1 * v1.w + a2 * v2.w + a3 * v3.w + bb.w;
  o.x = o.x > 0.f ? o.x : expm1f(o.x);
  o.y = o.y > 0.f ? o.y : expm1f(o.y);
  o.z = o.z > 0.f ? o.z : expm1f(o.z);
  o.w = o.w > 0.f ? o.w : expm1f(o.w);

  const float w00 = W2[(c + 0) * 2 + 0], w01 = W2[(c + 0) * 2 + 1];
  const float w10 = W2[(c + 1) * 2 + 0], w11 = W2[(c + 1) * 2 + 1];
  const float w20 = W2[(c + 2) * 2 + 0], w21 = W2[(c + 2) * 2 + 1];
  const float w30 = W2[(c + 3) * 2 + 0], w31 = W2[(c + 3) * 2 + 1];
  float p0 = o.x * w00 + o.y * w10 + o.z * w20 + o.w * w30;
  float p1 = o.x * w01 + o.y * w11 + o.z * w21 + o.w * w31;
#pragma unroll
  for (int off = 1; off < 64; off <<= 1) {
    p0 += __shfl_xor(p0, off);
    p1 += __shfl_xor(p1, off);
  }
  if (lane == 0) {
    g2[(size_t)n * 2]     = p0;
    g2[(size_t)n * 2 + 1] = p1;
    asrc2[n] = p0 * as2[0] + p1 * as2[1];
    adst2[n] = p0 * ad2[0] + p1 * ad2[1];
  }
}

// ---------------------------------------------------------------------------
// Final aggregation (H=1, F=2) + bias -> d_out
// ---------------------------------------------------------------------------
__global__ __launch_bounds__(256) void final_kernel(const int* __restrict__ nbr,
                                                    const float* __restrict__ g2,
                                                    const float* __restrict__ asrc2,
                                                    const float* __restrict__ adst2,
                                                    const float* __restrict__ b2,
                                                    float* __restrict__ out) {
  const int n = blockIdx.x * 256 + threadIdx.x;
  int4 nb = *(const int4*)&nbr[(size_t)n * 4];
  const float ad = adst2[n];
  float e0 = leaky02(asrc2[nb.x] + ad);
  float e1 = leaky02(asrc2[nb.y] + ad);
  float e2 = leaky02(asrc2[nb.z] + ad);
  float e3 = leaky02(asrc2[nb.w] + ad);
  float m = fmaxf(fmaxf(e0, e1), fmaxf(e2, e3));
  float x0 = expf(e0 - m), x1 = expf(e1 - m), x2 = expf(e2 - m), x3 = expf(e3 - m);
  float s = x0 + x1 + x2 + x3;
  float o0 = (x0 * g2[(size_t)nb.x * 2] + x1 * g2[(size_t)nb.y * 2] +
              x2 * g2[(size_t)nb.z * 2] + x3 * g2[(size_t)nb.w * 2]) / s;
  float o1 = (x0 * g2[(size_t)nb.x * 2 + 1] + x1 * g2[(size_t)nb.y * 2 + 1] +
              x2 * g2[(size_t)nb.z * 2 + 1] + x3 * g2[(size_t)nb.w * 2 + 1]) / s;
  out[(size_t)n * 2]     = o0 + b2[0];
  out[(size_t)n * 2 + 1] = o1 + b2[1];
}

extern "C" void kernel_launch(void* const* d_in, const int* in_sizes, int n_in,
                              void* d_out, int out_size, void* d_ws, size_t ws_size,
                              hipStream_t stream) {
  const float* coords = (const float*)d_in[0];
  const float* x   = (const float*)d_in[1];
  const float* W0  = (const float*)d_in[2];
  const float* as0 = (const float*)d_in[3];
  const float* ad0 = (const float*)d_in[4];
  const float* b0  = (const float*)d_in[5];
  const float* W1  = (const float*)d_in[6];
  const float* as1 = (const float*)d_in[7];
  const float* ad1 = (const float*)d_in[8];
  const float* b1  = (const float*)d_in[9];
  const float* W2  = (const float*)d_in[10];
  const float* as2 = (const float*)d_in[11];
  const float* ad2 = (const float*)d_in[12];
  const float* b2  = (const float*)d_in[13];
  float* out = (float*)d_out;

  // workspace carve-up
  float* g     = (float*)d_ws;                       // N*256
  float* y     = g + (size_t)Nn * 256;               // N*256
  int*   nbr   = (int*)(y + (size_t)Nn * 256);       // N*4
  float* asrc  = (float*)(nbr + (size_t)Nn * 4);     // N*4
  float* adst  = asrc + (size_t)Nn * 4;              // N*4
  float* g2    = adst + (size_t)Nn * 4;              // N*2
  float* s2    = g2 + (size_t)Nn * 2;                // N
  float* d2    = s2 + (size_t)Nn;                    // N
  unsigned short* Wth = (unsigned short*)(d2 + (size_t)Nn);  // 256*256
  unsigned short* Wtl = Wth + 256 * 256;                     // 256*256
  float2* pts  = (float2*)(Wtl + 256 * 256);         // Bn*Pn float2
  int* ids     = (int*)(pts + (size_t)Bn * Pn);      // Bn*Pn
  int* counts  = ids + (size_t)Bn * Pn;              // Bn*NBIN
  int* starts  = counts + Bn * NBIN;                 // Bn*NBIN
  int* cursor  = starts + Bn * NBIN;                 // Bn*NBIN

  // kNN: bin -> scan -> scatter -> ring query
  hipMemsetAsync(counts, 0, Bn * NBIN * sizeof(int), stream);
  bin_count<<<Nn / 256, 256, 0, stream>>>(coords, counts);
  bin_scan<<<Bn, NBIN, 0, stream>>>(counts, starts, cursor);
  bin_scatter<<<Nn / 256, 256, 0, stream>>>(coords, cursor, pts, ids);
  knn_query<<<Nn / 256, 256, 0, stream>>>(coords, starts, counts, pts, ids, nbr);

  // Layer 0 (attn projections fused into gemm epilogue)
  wt_kernel<<<256, 256, 0, stream>>>(W0, Wth, Wtl);
  gemm_bf3<<<dim3(2, Nn / 128), 256, 0, stream>>>(x, Wth, Wtl, as0, ad0, g, asrc, adst);
  aggregate_fused<<<Nn / 4, 256, 0, stream>>>(g, nbr, asrc, adst, b0, y);

  // Layer 1
  wt_kernel<<<256, 256, 0, stream>>>(W1, Wth, Wtl);
  gemm_bf3<<<dim3(2, Nn / 128), 256, 0, stream>>>(y, Wth, Wtl, as1, ad1, g, asrc, adst);
  aggregate_h2<<<Nn / 4, 256, 0, stream>>>(g, nbr, asrc, adst, b1, W2, as2, ad2,
                                           g2, s2, d2);

  // Final aggregation (H=1, F=2)
  final_kernel<<<Nn / 256, 256, 0, stream>>>(nbr, g2, s2, d2, b2, out);
}

// Round 8
// 635.403 us; speedup vs baseline: 2.1794x; 1.1121x over previous
//
#include <hip/hip_runtime.h>
#include <math.h>

// Problem constants (B=16, P=8192)
constexpr int Bn = 16, Pn = 8192, Nn = 16 * 8192;
constexpr int GB = 32;            // bins per axis
constexpr int NBIN = GB * GB;     // 1024 bins per batch

typedef __attribute__((ext_vector_type(8))) short short8;
typedef __attribute__((ext_vector_type(4))) float f32x4;

// f32 -> bf16 (round-to-nearest-even), and back
__device__ __forceinline__ unsigned short f2bf(float f) {
  unsigned u = __builtin_bit_cast(unsigned, f);
  unsigned r = (u + 0x7FFFu + ((u >> 16) & 1u)) >> 16;
  return (unsigned short)r;
}
__device__ __forceinline__ float bf2f(unsigned short h) {
  unsigned u = ((unsigned)h) << 16;
  return __builtin_bit_cast(float, u);
}

// ---------------------------------------------------------------------------
// kNN: exact spatial-grid kNN (unchanged from R5 — no longer a top cost).
// ---------------------------------------------------------------------------
__global__ __launch_bounds__(256) void bin_count(const float* __restrict__ coords,
                                                 int* __restrict__ counts) {
  const int n = blockIdx.x * 256 + threadIdx.x;
  const int b = n >> 13;
  float2 c = ((const float2*)coords)[n];
  int bx = min(GB - 1, (int)(c.x * (float)GB));
  int by = min(GB - 1, (int)(c.y * (float)GB));
  atomicAdd(&counts[b * NBIN + by * GB + bx], 1);
}

__global__ __launch_bounds__(1024) void bin_scan(const int* __restrict__ counts,
                                                 int* __restrict__ starts,
                                                 int* __restrict__ cursor) {
  __shared__ int s[NBIN];
  const int b = blockIdx.x, t = threadIdx.x;
  const int v = counts[b * NBIN + t];
  s[t] = v;
  __syncthreads();
  for (int off = 1; off < NBIN; off <<= 1) {
    int x = (t >= off) ? s[t - off] : 0;
    __syncthreads();
    s[t] += x;
    __syncthreads();
  }
  const int excl = s[t] - v;
  starts[b * NBIN + t] = excl;
  cursor[b * NBIN + t] = excl;
}

__global__ __launch_bounds__(256) void bin_scatter(const float* __restrict__ coords,
                                                   int* __restrict__ cursor,
                                                   float2* __restrict__ pts,
                                                   int* __restrict__ ids) {
  const int n = blockIdx.x * 256 + threadIdx.x;
  const int b = n >> 13, p = n & (Pn - 1);
  float2 c = ((const float2*)coords)[n];
  int bx = min(GB - 1, (int)(c.x * (float)GB));
  int by = min(GB - 1, (int)(c.y * (float)GB));
  int slot = atomicAdd(&cursor[b * NBIN + by * GB + bx], 1);
  pts[(size_t)b * Pn + slot] = c;
  ids[(size_t)b * Pn + slot] = p;
}

__global__ __launch_bounds__(256) void knn_query(const float* __restrict__ coords,
                                                 const int* __restrict__ starts,
                                                 const int* __restrict__ counts,
                                                 const float2* __restrict__ pts,
                                                 const int* __restrict__ ids,
                                                 int* __restrict__ nbr) {
  const int n = blockIdx.x * 256 + threadIdx.x;
  const int b = n >> 13;
  const float2 q = ((const float2*)coords)[n];
  const float qx = q.x, qy = q.y;
  const float w = 1.0f / (float)GB;
  const int bx = min(GB - 1, (int)(qx * (float)GB));
  const int by = min(GB - 1, (int)(qy * (float)GB));
  const float2* bp = pts + (size_t)b * Pn;
  const int* bi = ids + (size_t)b * Pn;
  const int* bs = starts + b * NBIN;
  const int* bc = counts + b * NBIN;

  float d0v = 3.4e38f, d1v = 3.4e38f, d2v = 3.4e38f, d3v = 3.4e38f;
  int i0v = 0x7fffffff, i1v = 0x7fffffff, i2v = 0x7fffffff, i3v = 0x7fffffff;

#define LLT(da, ia, db, ib) ((da) < (db) || ((da) == (db) && (ia) < (ib)))
#define LEX_INSERT(dd, jj)                                              \
  if (LLT(dd, jj, d3v, i3v)) {                                          \
    if (LLT(dd, jj, d2v, i2v)) {                                        \
      d3v = d2v; i3v = i2v;                                             \
      if (LLT(dd, jj, d1v, i1v)) {                                      \
        d2v = d1v; i2v = i1v;                                           \
        if (LLT(dd, jj, d0v, i0v)) { d1v = d0v; i1v = i0v; d0v = dd; i0v = jj; } \
        else { d1v = dd; i1v = jj; }                                    \
      } else { d2v = dd; i2v = jj; }                                    \
    } else { d3v = dd; i3v = jj; }                                      \
  }
#define SCAN_CELL(xx, yy)                                               \
  {                                                                     \
    const int cell = (yy) * GB + (xx);                                  \
    const int s0 = bs[cell], cnt = bc[cell];                            \
    for (int s = s0; s < s0 + cnt; ++s) {                               \
      float2 pp = bp[s];                                                \
      int jj = bi[s];                                                   \
      float dx = qx - pp.x, dy = qy - pp.y;                             \
      float dd = __fadd_rn(__fmul_rn(dx, dx), __fmul_rn(dy, dy));       \
      LEX_INSERT(dd, jj);                                               \
    }                                                                   \
  }

  for (int k = 0; k < GB; ++k) {
    const int xlo = bx - k, xhi = bx + k, ylo = by - k, yhi = by + k;
    const int cxlo = max(0, xlo), cxhi = min(GB - 1, xhi);
    const int cylo = max(0, ylo), cyhi = min(GB - 1, yhi);
    for (int yy = cylo; yy <= cyhi; ++yy) {
      const bool edge = (yy == ylo) || (yy == yhi);
      if (edge || k == 0) {
        for (int xx = cxlo; xx <= cxhi; ++xx) SCAN_CELL(xx, yy);
      } else {
        if (xlo >= 0) SCAN_CELL(xlo, yy);
        if (xhi <= GB - 1) SCAN_CELL(xhi, yy);
      }
    }
    float m = 1e30f;
    bool open = false;
    if (xlo > 0)      { m = fminf(m, qx - (float)xlo * w); open = true; }
    if (xhi < GB - 1) { m = fminf(m, (float)(xhi + 1) * w - qx); open = true; }
    if (ylo > 0)      { m = fminf(m, qy - (float)ylo * w); open = true; }
    if (yhi < GB - 1) { m = fminf(m, (float)(yhi + 1) * w - qy); open = true; }
    if (!open) break;
    m -= 1e-6f;
    if (d3v < 3.0e38f && m > 0.f && __fmul_rn(m, m) >= d3v) break;
  }
#undef SCAN_CELL
#undef LEX_INSERT
#undef LLT

  const int base = b * Pn;
  *(int4*)&nbr[(size_t)n * 4] =
      make_int4(base + i0v, base + i1v, base + i2v, base + i3v);
}

// ---------------------------------------------------------------------------
// W [256][256] f32 (row-major [k][n]) -> Wt_h/Wt_l bf16 [n][k] (transposed)
// ---------------------------------------------------------------------------
__global__ __launch_bounds__(256) void wt_kernel(const float* __restrict__ W,
                                                 unsigned short* __restrict__ Wth,
                                                 unsigned short* __restrict__ Wtl) {
  const int k = blockIdx.x, n = threadIdx.x;
  float v = W[k * 256 + n];
  unsigned short h = f2bf(v);
  unsigned short l = f2bf(v - bf2f(h));
  Wth[n * 256 + k] = h;
  Wtl[n * 256 + k] = l;
}

// ---------------------------------------------------------------------------
// bf16x3 MFMA GEMM v3 + fused attention projections.
// Swapped-operand MFMA: acc[fr][fc] = mfma(Bfrag, Afrag, acc) computes the
// C^T fragment => lane holds row = lrow, cols = cg..cg+3 CONSECUTIVE ->
// float4 C stores (kills partial-line write amplification seen in R7:
// WRITE_SIZE 313MB vs 134MB ideal). B fragments read direct from global
// (W 256KB, L2-resident) -> no B LDS, 18.4KB LDS total.
// ---------------------------------------------------------------------------
__global__ __launch_bounds__(256, 3) void gemm_bf3(const float* __restrict__ A,
                                                   const unsigned short* __restrict__ Bth,
                                                   const unsigned short* __restrict__ Btl,
                                                   const float* __restrict__ att_src,
                                                   const float* __restrict__ att_dst,
                                                   float* __restrict__ C,
                                                   float* __restrict__ asrc,
                                                   float* __restrict__ adst) {
  __shared__ unsigned short Ah[128][36], Al[128][36];  // stride 72B: 16 rows -> 16 banks
  const int t = threadIdx.x;
  const int row0 = blockIdx.y * 128;
  const int col0 = blockIdx.x * 128;
  const int wid = t >> 6, lane = t & 63;
  const int wr = (wid >> 1) * 64, wc = (wid & 1) * 64;
  const int lrow = lane & 15, lko = (lane >> 4) * 8;
  const int cg = (lane >> 4) * 4;  // column sub-group within a 16-col fragment

  f32x4 acc[4][4];  // [fr = A-row block][fc = W-col block]
#pragma unroll
  for (int i = 0; i < 4; ++i)
#pragma unroll
    for (int j = 0; j < 4; ++j) acc[i][j] = {0.f, 0.f, 0.f, 0.f};

  float4 av[4];

#define GLOAD(ktv)                                                          \
  {                                                                         \
    const int k0 = (ktv) * 32;                                              \
    _Pragma("unroll")                                                       \
    for (int i = 0; i < 4; ++i) {                                           \
      const int idx = t + i * 256;                                          \
      const int row = idx >> 3, kq = idx & 7;                               \
      av[i] = *(const float4*)&A[(size_t)(row0 + row) * 256 + k0 + kq * 4]; \
    }                                                                       \
  }

  GLOAD(0);
  for (int kt = 0; kt < 8; ++kt) {
    __syncthreads();  // previous iter's A frag reads done
#pragma unroll
    for (int i = 0; i < 4; ++i) {
      const int idx = t + i * 256;
      const int row = idx >> 3, kq = idx & 7;
      const float vv[4] = {av[i].x, av[i].y, av[i].z, av[i].w};
      unsigned short hh[4], ll[4];
#pragma unroll
      for (int e = 0; e < 4; ++e) {
        hh[e] = f2bf(vv[e]);
        ll[e] = f2bf(vv[e] - bf2f(hh[e]));
      }
      *(ushort4*)&Ah[row][kq * 4] = make_ushort4(hh[0], hh[1], hh[2], hh[3]);
      *(ushort4*)&Al[row][kq * 4] = make_ushort4(ll[0], ll[1], ll[2], ll[3]);
    }
    __syncthreads();
    if (kt < 7) GLOAD(kt + 1);  // prefetch next A tile under this iter's MFMA

    // B fragments direct from global (L2-hot; 16B contiguous per lane)
    short8 bfh[4], bfl[4];
#pragma unroll
    for (int f = 0; f < 4; ++f) {
      const size_t boff = (size_t)(col0 + wc + f * 16 + lrow) * 256 + kt * 32 + lko;
      bfh[f] = *(const short8*)&Bth[boff];
      bfl[f] = *(const short8*)&Btl[boff];
    }
    short8 afh[4], afl[4];
#pragma unroll
    for (int f = 0; f < 4; ++f) {
      afh[f] = *(const short8*)&Ah[wr + f * 16 + lrow][lko];
      afl[f] = *(const short8*)&Al[wr + f * 16 + lrow][lko];
    }
#pragma unroll
    for (int fr = 0; fr < 4; ++fr)
#pragma unroll
      for (int fc = 0; fc < 4; ++fc) {
        acc[fr][fc] = __builtin_amdgcn_mfma_f32_16x16x32_bf16(bfh[fc], afh[fr], acc[fr][fc], 0, 0, 0);
        acc[fr][fc] = __builtin_amdgcn_mfma_f32_16x16x32_bf16(bfl[fc], afh[fr], acc[fr][fc], 0, 0, 0);
        acc[fr][fc] = __builtin_amdgcn_mfma_f32_16x16x32_bf16(bfh[fc], afl[fr], acc[fr][fc], 0, 0, 0);
      }
  }
#undef GLOAD

  // --- C stores: swapped layout => lane owns row=lrow, cols cg..cg+3 ---
#pragma unroll
  for (int fr = 0; fr < 4; ++fr) {
    const int row = row0 + wr + fr * 16 + lrow;
#pragma unroll
    for (int fc = 0; fc < 4; ++fc) {
      const int col = col0 + wc + fc * 16 + cg;
      *(f32x4*)&C[(size_t)row * 256 + col] = acc[fr][fc];
    }
  }

  // --- fused attention projections: this wave's 64 cols == head h ---
  const int h = (col0 >> 6) + (wid & 1);
  float4 asv[4], adv[4];
#pragma unroll
  for (int fc = 0; fc < 4; ++fc) {
    asv[fc] = *(const float4*)&att_src[h * 64 + fc * 16 + cg];
    adv[fc] = *(const float4*)&att_dst[h * 64 + fc * 16 + cg];
  }
#pragma unroll
  for (int fr = 0; fr < 4; ++fr) {
    float ps = 0.f, pd = 0.f;
#pragma unroll
    for (int fc = 0; fc < 4; ++fc) {
      ps += acc[fr][fc][0] * asv[fc].x + acc[fr][fc][1] * asv[fc].y +
            acc[fr][fc][2] * asv[fc].z + acc[fr][fc][3] * asv[fc].w;
      pd += acc[fr][fc][0] * adv[fc].x + acc[fr][fc][1] * adv[fc].y +
            acc[fr][fc][2] * adv[fc].z + acc[fr][fc][3] * adv[fc].w;
    }
    ps += __shfl_xor(ps, 16); ps += __shfl_xor(ps, 32);
    pd += __shfl_xor(pd, 16); pd += __shfl_xor(pd, 32);
    if (lane < 16) {
      const int row = row0 + wr + fr * 16 + lrow;
      asrc[(size_t)row * 4 + h] = ps;
      adst[(size_t)row * 4 + h] = pd;
    }
  }
}

__device__ __forceinline__ float leaky02(float x) { return x >= 0.f ? x : 0.2f * x; }

// ---------------------------------------------------------------------------
// Fused alpha + aggregate (+ELU) -> y.
// ---------------------------------------------------------------------------
__global__ __launch_bounds__(256) void aggregate_fused(const float* __restrict__ g,
                                                       const int* __restrict__ nbr,
                                                       const float* __restrict__ asrc,
                                                       const float* __restrict__ adst,
                                                       const float* __restrict__ bias,
                                                       float* __restrict__ y) {
  const int t = threadIdx.x;
  const int lane = t & 63;
  const int n = blockIdx.x * 4 + (t >> 6);
  int4 nb = *(const int4*)&nbr[(size_t)n * 4];
  const int h = lane >> 4;
  const float adh = adst[(size_t)n * 4 + h];
  float e0 = leaky02(asrc[(size_t)nb.x * 4 + h] + adh);
  float e1 = leaky02(asrc[(size_t)nb.y * 4 + h] + adh);
  float e2 = leaky02(asrc[(size_t)nb.z * 4 + h] + adh);
  float e3 = leaky02(asrc[(size_t)nb.w * 4 + h] + adh);
  float m = fmaxf(fmaxf(fmaxf(e0, e1), e2), e3);
  float x0 = expf(e0 - m), x1 = expf(e1 - m), x2 = expf(e2 - m), x3 = expf(e3 - m);
  float s = ((x0 + x1) + x2) + x3;
  const float a0 = x0 / s, a1 = x1 / s, a2 = x2 / s, a3 = x3 / s;

  const int c = lane * 4;
  float4 v0 = *(const float4*)&g[(size_t)nb.x * 256 + c];
  float4 v1 = *(const float4*)&g[(size_t)nb.y * 256 + c];
  float4 v2 = *(const float4*)&g[(size_t)nb.z * 256 + c];
  float4 v3 = *(const float4*)&g[(size_t)nb.w * 256 + c];
  float4 bb = *(const float4*)&bias[c];
  float4 o;
  o.x = a0 * v0.x + a1 * v1.x + a2 * v2.x + a3 * v3.x + bb.x;
  o.y = a0 * v0.y + a1 * v1.y + a2 * v2.y + a3 * v3.y + bb.y;
  o.z = a0 * v0.z + a1 * v1.z + a2 * v2.z + a3 * v3.z + bb.z;
  o.w = a0 * v0.w + a1 * v1.w + a2 * v2.w + a3 * v3.w + bb.w;
  o.x = o.x > 0.f ? o.x : expm1f(o.x);
  o.y = o.y > 0.f ? o.y : expm1f(o.y);
  o.z = o.z > 0.f ? o.z : expm1f(o.z);
  o.w = o.w > 0.f ? o.w : expm1f(o.w);
  *(float4*)&y[(size_t)n * 256 + c] = o;
}

// ---------------------------------------------------------------------------
// Layer-1 aggregate fused with ELU + head2 projection.
// ---------------------------------------------------------------------------
__global__ __launch_bounds__(256) void aggregate_h2(const float* __restrict__ g,
                                                    const int* __restrict__ nbr,
                                                    const float* __restrict__ asrc,
                                                    const float* __restrict__ adst,
                                                    const float* __restrict__ bias,
                                                    const float* __restrict__ W2,
                                                    const float* __restrict__ as2,
                                                    const float* __restrict__ ad2,
                                                    float* __restrict__ g2,
                                                    float* __restrict__ asrc2,
                                                    float* __restrict__ adst2) {
  const int t = threadIdx.x;
  const int lane = t & 63;
  const int n = blockIdx.x * 4 + (t >> 6);
  int4 nb = *(const int4*)&nbr[(size_t)n * 4];
  const int h = lane >> 4;
  const float adh = adst[(size_t)n * 4 + h];
  float e0 = leaky02(asrc[(size_t)nb.x * 4 + h] + adh);
  float e1 = leaky02(asrc[(size_t)nb.y * 4 + h] + adh);
  float e2 = leaky02(asrc[(size_t)nb.z * 4 + h] + adh);
  float e3 = leaky02(asrc[(size_t)nb.w * 4 + h] + adh);
  float m = fmaxf(fmaxf(fmaxf(e0, e1), e2), e3);
  float x0 = expf(e0 - m), x1 = expf(e1 - m), x2 = expf(e2 - m), x3 = expf(e3 - m);
  float s = ((x0 + x1) + x2) + x3;
  const float a0 = x0 / s, a1 = x1 / s, a2 = x2 / s, a3 = x3 / s;

  const int c = lane * 4;
  float4 v0 = *(const float4*)&g[(size_t)nb.x * 256 + c];
  float4 v1 = *(const float4*)&g[(size_t)nb.y * 256 + c];
  float4 v2 = *(const float4*)&g[(size_t)nb.z * 256 + c];
  float4 v3 = *(const float4*)&g[(size_t)nb.w * 256 + c];
  float4 bb = *(const float4*)&bias[c];
  float4 o;
  o.x = a0 * v0.x + a1 * v1.x + a2 * v2.x + a3 * v3.x + bb.x;
  o.y = a0 * v0.y + a1 * v1.y + a2 * v2.y + a3 * v3.y + bb.y;
  o.z = a0 * v0.z + a1 * v1.z + a2 * v2.z + a3 * v3.z + bb.z;
  o.w = a0 * v0.w + a1 * v1.w + a2 * v2.w + a3 * v3.w + bb.w;
  o.x = o.x > 0.f ? o.x : expm1f(o.x);
  o.y = o.y > 0.f ? o.y : expm1f(o.y);
  o.z = o.z > 0.f ? o.z : expm1f(o.z);
  o.w = o.w > 0.f ? o.w : expm1f(o.w);

  const float w00 = W2[(c + 0) * 2 + 0], w01 = W2[(c + 0) * 2 + 1];
  const float w10 = W2[(c + 1) * 2 + 0], w11 = W2[(c + 1) * 2 + 1];
  const float w20 = W2[(c + 2) * 2 + 0], w21 = W2[(c + 2) * 2 + 1];
  const float w30 = W2[(c + 3) * 2 + 0], w31 = W2[(c + 3) * 2 + 1];
  float p0 = o.x * w00 + o.y * w10 + o.z * w20 + o.w * w30;
  float p1 = o.x * w01 + o.y * w11 + o.z * w21 + o.w * w31;
#pragma unroll
  for (int off = 1; off < 64; off <<= 1) {
    p0 += __shfl_xor(p0, off);
    p1 += __shfl_xor(p1, off);
  }
  if (lane == 0) {
    g2[(size_t)n * 2]     = p0;
    g2[(size_t)n * 2 + 1] = p1;
    asrc2[n] = p0 * as2[0] + p1 * as2[1];
    adst2[n] = p0 * ad2[0] + p1 * ad2[1];
  }
}

// ---------------------------------------------------------------------------
// Final aggregation (H=1, F=2) + bias -> d_out
// ---------------------------------------------------------------------------
__global__ __launch_bounds__(256) void final_kernel(const int* __restrict__ nbr,
                                                    const float* __restrict__ g2,
                                                    const float* __restrict__ asrc2,
                                                    const float* __restrict__ adst2,
                                                    const float* __restrict__ b2,
                                                    float* __restrict__ out) {
  const int n = blockIdx.x * 256 + threadIdx.x;
  int4 nb = *(const int4*)&nbr[(size_t)n * 4];
  const float ad = adst2[n];
  float e0 = leaky02(asrc2[nb.x] + ad);
  float e1 = leaky02(asrc2[nb.y] + ad);
  float e2 = leaky02(asrc2[nb.z] + ad);
  float e3 = leaky02(asrc2[nb.w] + ad);
  float m = fmaxf(fmaxf(e0, e1), fmaxf(e2, e3));
  float x0 = expf(e0 - m), x1 = expf(e1 - m), x2 = expf(e2 - m), x3 = expf(e3 - m);
  float s = x0 + x1 + x2 + x3;
  float o0 = (x0 * g2[(size_t)nb.x * 2] + x1 * g2[(size_t)nb.y * 2] +
              x2 * g2[(size_t)nb.z * 2] + x3 * g2[(size_t)nb.w * 2]) / s;
  float o1 = (x0 * g2[(size_t)nb.x * 2 + 1] + x1 * g2[(size_t)nb.y * 2 + 1] +
              x2 * g2[(size_t)nb.z * 2 + 1] + x3 * g2[(size_t)nb.w * 2 + 1]) / s;
  out[(size_t)n * 2]     = o0 + b2[0];
  out[(size_t)n * 2 + 1] = o1 + b2[1];
}

extern "C" void kernel_launch(void* const* d_in, const int* in_sizes, int n_in,
                              void* d_out, int out_size, void* d_ws, size_t ws_size,
                              hipStream_t stream) {
  const float* coords = (const float*)d_in[0];
  const float* x   = (const float*)d_in[1];
  const float* W0  = (const float*)d_in[2];
  const float* as0 = (const float*)d_in[3];
  const float* ad0 = (const float*)d_in[4];
  const float* b0  = (const float*)d_in[5];
  const float* W1  = (const float*)d_in[6];
  const float* as1 = (const float*)d_in[7];
  const float* ad1 = (const float*)d_in[8];
  const float* b1  = (const float*)d_in[9];
  const float* W2  = (const float*)d_in[10];
  const float* as2 = (const float*)d_in[11];
  const float* ad2 = (const float*)d_in[12];
  const float* b2  = (const float*)d_in[13];
  float* out = (float*)d_out;

  // workspace carve-up
  float* g     = (float*)d_ws;                       // N*256
  float* y     = g + (size_t)Nn * 256;               // N*256
  int*   nbr   = (int*)(y + (size_t)Nn * 256);       // N*4
  float* asrc  = (float*)(nbr + (size_t)Nn * 4);     // N*4
  float* adst  = asrc + (size_t)Nn * 4;              // N*4
  float* g2    = adst + (size_t)Nn * 4;              // N*2
  float* s2    = g2 + (size_t)Nn * 2;                // N
  float* d2    = s2 + (size_t)Nn;                    // N
  unsigned short* Wth = (unsigned short*)(d2 + (size_t)Nn);  // 256*256
  unsigned short* Wtl = Wth + 256 * 256;                     // 256*256
  float2* pts  = (float2*)(Wtl + 256 * 256);         // Bn*Pn float2
  int* ids     = (int*)(pts + (size_t)Bn * Pn);      // Bn*Pn
  int* counts  = ids + (size_t)Bn * Pn;              // Bn*NBIN
  int* starts  = counts + Bn * NBIN;                 // Bn*NBIN
  int* cursor  = starts + Bn * NBIN;                 // Bn*NBIN

  // kNN: bin -> scan -> scatter -> ring query
  hipMemsetAsync(counts, 0, Bn * NBIN * sizeof(int), stream);
  bin_count<<<Nn / 256, 256, 0, stream>>>(coords, counts);
  bin_scan<<<Bn, NBIN, 0, stream>>>(counts, starts, cursor);
  bin_scatter<<<Nn / 256, 256, 0, stream>>>(coords, cursor, pts, ids);
  knn_query<<<Nn / 256, 256, 0, stream>>>(coords, starts, counts, pts, ids, nbr);

  // Layer 0 (attn projections fused into gemm epilogue)
  wt_kernel<<<256, 256, 0, stream>>>(W0, Wth, Wtl);
  gemm_bf3<<<dim3(2, Nn / 128), 256, 0, stream>>>(x, Wth, Wtl, as0, ad0, g, asrc, adst);
  aggregate_fused<<<Nn / 4, 256, 0, stream>>>(g, nbr, asrc, adst, b0, y);

  // Layer 1
  wt_kernel<<<256, 256, 0, stream>>>(W1, Wth, Wtl);
  gemm_bf3<<<dim3(2, Nn / 128), 256, 0, stream>>>(y, Wth, Wtl, as1, ad1, g, asrc, adst);
  aggregate_h2<<<Nn / 4, 256, 0, stream>>>(g, nbr, asrc, adst, b1, W2, as2, ad2,
                                           g2, s2, d2);

  // Final aggregation (H=1, F=2)
  final_kernel<<<Nn / 256, 256, 0, stream>>>(nbr, g2, s2, d2, b2, out);
}